// Round 14
// baseline (325.880 us; speedup 1.0000x reference)
//
#include <hip/hip_runtime.h>
#include <hip/hip_fp16.h>
#include <hip/hip_cooperative_groups.h>
#include <math.h>

namespace cg = cooperative_groups;

// ---------------------------------------------------------------------------
// HolographicPatternExtractor  (B=16, C=1, H=W=512)
//  outputs (flat f32): sims[16,64] | spatial[16,1024] | phase_feats[16,3] | holo[16,128]
// ---------------------------------------------------------------------------

#define PI_F 3.14159274f          // float(np.pi)
#define TWO_PI_F 6.28318548f

typedef _Float16 half8 __attribute__((ext_vector_type(8)));
typedef _Float16 h2 __attribute__((ext_vector_type(2)));
typedef float floatx4 __attribute__((ext_vector_type(4)));

// ---- workspace layout (dword offsets) ----
#define OFF_BIG   8388608
#define OFF_SMALL 25165824
#define NBIN 2048                 // magnitude histogram bins (fp16 bits>>4)

// ===========================================================================
// combined init: zero accumulators + twiddle table + weight repacks
// ===========================================================================
__global__ void __launch_bounds__(256) init_kernel(float* __restrict__ zp,
                                                   float2* __restrict__ tw,
                                                   const float* __restrict__ w2,
                                                   const float* __restrict__ w1,
                                                   _Float16* __restrict__ wrep,
                                                   _Float16* __restrict__ w1r) {
    int idx = blockIdx.x * 256 + threadIdx.x;
    if (idx < 82992) zp[idx] = 0.0f;
    if (idx < 512) {
        if (idx == 0) tw[0] = make_float2(1.f, 0.f);
        else {
            int h = 31 - __clz(idx);
            int H = 1 << h;
            float sn, cs;
            sincosf(-PI_F * (float)(idx - H) / (float)H, &sn, &cs);
            tw[idx] = make_float2(cs, sn);
        }
    }
    if (idx < 18432) {            // conv2 MFMA B-fragment
        int j = idx & 7;
        int lane = (idx >> 3) & 63;
        int nt = (idx >> 9) & 3;
        int tap = idx >> 11;
        int oc = nt * 16 + (lane & 15);
        int ic = (lane >> 4) * 8 + j;
        wrep[idx] = (_Float16)w2[(oc * 32 + ic) * 9 + tap];
    }
    if (idx < 1024) {             // conv1 MFMA B-fragment: [nt][lane][j]
        // PAIRED oc: nt=0 -> even oc (2m), nt=1 -> odd (2m+1) -> one h2 store
        int j = idx & 7;
        int lane = (idx >> 3) & 63;
        int nt = idx >> 9;
        int oc = 2 * (lane & 15) + nt;
        int k = (lane >> 4) * 8 + j;      // k = 2*tap + ch, pad >=18 with 0
        _Float16 v = (_Float16)0.f;
        if (k < 18) {
            int tap = k >> 1, ch = k & 1;
            v = (_Float16)w1[oc * 18 + ch * 9 + tap];
        }
        w1r[idx] = v;
    }
}

// ===========================================================================
// FFT row pass, REAL-PAIR packed: rows (2y, 2y+1) as one complex 512-pt DIF
// FFT; Hermitian untangle; spectra stored as half2 (fp16 re/im).
// ===========================================================================
__global__ void __launch_bounds__(256) fft_rows2(const float* __restrict__ img,
                                                 const float2* __restrict__ twg,
                                                 h2* __restrict__ rowhf) {
    __shared__ float2 s[512];
    __shared__ float2 tw[512];
    const int t = threadIdx.x;
    const long long rbase = (long long)blockIdx.x * 1024;   // row-pair base elem
    const float* x0 = img + rbase;
    const float* x1 = x0 + 512;

    for (int i = t; i < 512; i += 256) tw[i] = twg[i];
    for (int i = t; i < 512; i += 256) s[i] = make_float2(x0[i], x1[i]);
    __syncthreads();
#pragma unroll
    for (int st = 9; st >= 1; --st) {
        const int half = 1 << (st - 1);
        const int pos = t & (half - 1);
        const int grp = t >> (st - 1);
        const int i1 = (grp << st) + pos;
        const int i2 = i1 + half;
        float2 w = tw[half + pos];
        float2 a = s[i1], b = s[i2];
        float dx = a.x - b.x, dy = a.y - b.y;
        s[i1] = make_float2(a.x + b.x, a.y + b.y);
        s[i2] = make_float2(dx * w.x - dy * w.y, dx * w.y + dy * w.x);
        __syncthreads();
    }
    // untangle: X0(k)=(Z(k)+conj(Z(-k)))/2, X1(k)=-i(Z(k)-conj(Z(-k)))/2
    for (int i = t; i < 512; i += 256) {
        int k = __brev((unsigned)i) >> 23;
        int kp = (512 - k) & 511;
        int jp = __brev((unsigned)kp) >> 23;
        float2 Z = s[i], Zp = s[jp];
        rowhf[rbase + i]       = h2{(_Float16)(0.5f * (Z.x + Zp.x)),
                                    (_Float16)(0.5f * (Z.y - Zp.y))};
        rowhf[rbase + 512 + i] = h2{(_Float16)(0.5f * (Z.y + Zp.y)),
                                    (_Float16)(-0.5f * (Z.x - Zp.x))};
    }
}

// ===========================================================================
// COOPERATIVE fused column-FFT + phase stats + histogram + threshold +
// candidate collection. 256 blocks x 512 threads (1 block/CU co-resident).
// Block = (batch b, 32 columns in 2 groups of 16). Register FFT per column
// (stages h>=32 in-register, h=16..1 via shfl_xor). Mags kept PACKED IN
// REGISTERS (32 fp16/thread) — no magT buffer. grid.sync(), then threshold
// via LDS suffix-scan of the 2048-bin histogram, then register-resident
// candidate append. Replaces fft_cols + thresh + collect and 67 MB of HBM.
// ===========================================================================
#define TK_CAP 4096
__global__ void __launch_bounds__(512) fftcol_coop(const h2* __restrict__ rowhf,
                                                   const float2* __restrict__ twg,
                                                   float* __restrict__ psum,
                                                   float* __restrict__ psumsq,
                                                   unsigned* __restrict__ phist,
                                                   unsigned* __restrict__ mhist,
                                                   float* __restrict__ cand,
                                                   unsigned* __restrict__ ccnt) {
    __shared__ h2 sh[16 * 512];                 // 32 KB
    __shared__ float2 tw[512];                  // 4 KB
    __shared__ unsigned ph[64];
    __shared__ unsigned mh[NBIN];               // 8 KB
    __shared__ float red[16];
    __shared__ unsigned scanA[512], scanB[512]; // 4 KB
    __shared__ int seltb;
    const int t = threadIdx.x;
    const int b = blockIdx.x >> 4;
    const int xg = blockIdx.x & 15;             // 32 columns: xg*32 .. xg*32+31

    for (int i = t; i < 512; i += 512) tw[i] = twg[i];
    if (t < 64) ph[t] = 0u;
    for (int i = t; i < NBIN; i += 512) mh[i] = 0u;

    const int c = t >> 5;                       // 0..15 (column within group)
    const int j = t & 31;
    float lsum = 0.f, lsq = 0.f;
    unsigned mgp[16];                           // 32 fp16 mags packed

#pragma unroll 1
    for (int cgi = 0; cgi < 2; ++cgi) {
        const int x0 = xg * 32 + cgi * 16;
        __syncthreads();                        // sh safe to overwrite
        for (int idx = t; idx < 16 * 512; idx += 512) {
            int y = idx >> 4, cc = idx & 15;
            sh[cc * 512 + y] = rowhf[((size_t)(b * 512 + y)) * 512 + x0 + cc];
        }
        __syncthreads();

        float2 v[16];
#pragma unroll
        for (int r = 0; r < 16; ++r) {
            h2 hv = sh[c * 512 + j + 32 * r];
            v[r] = make_float2((float)hv[0], (float)hv[1]);
        }
        __syncthreads();                        // all reads done before next stage

        // ---- stage h=256 ----
#pragma unroll
        for (int r = 0; r < 8; ++r) {
            float2 w = tw[256 + j + 32 * r];
            float2 a = v[r], bb = v[r + 8];
            float dx = a.x - bb.x, dy = a.y - bb.y;
            v[r]     = make_float2(a.x + bb.x, a.y + bb.y);
            v[r + 8] = make_float2(dx * w.x - dy * w.y, dx * w.y + dy * w.x);
        }
        // ---- stage h=128 ----
#pragma unroll
        for (int g = 0; g < 2; ++g)
#pragma unroll
            for (int rr = 0; rr < 4; ++rr) {
                int r = g * 8 + rr;
                float2 w = tw[128 + j + 32 * rr];
                float2 a = v[r], bb = v[r + 4];
                float dx = a.x - bb.x, dy = a.y - bb.y;
                v[r]     = make_float2(a.x + bb.x, a.y + bb.y);
                v[r + 4] = make_float2(dx * w.x - dy * w.y, dx * w.y + dy * w.x);
            }
        // ---- stage h=64 ----
#pragma unroll
        for (int g = 0; g < 4; ++g)
#pragma unroll
            for (int rr = 0; rr < 2; ++rr) {
                int r = g * 4 + rr;
                float2 w = tw[64 + j + 32 * rr];
                float2 a = v[r], bb = v[r + 2];
                float dx = a.x - bb.x, dy = a.y - bb.y;
                v[r]     = make_float2(a.x + bb.x, a.y + bb.y);
                v[r + 2] = make_float2(dx * w.x - dy * w.y, dx * w.y + dy * w.x);
            }
        // ---- stage h=32 ----
        {
            float2 w = tw[32 + j];
#pragma unroll
            for (int g = 0; g < 8; ++g) {
                int r = g * 2;
                float2 a = v[r], bb = v[r + 1];
                float dx = a.x - bb.x, dy = a.y - bb.y;
                v[r]     = make_float2(a.x + bb.x, a.y + bb.y);
                v[r + 1] = make_float2(dx * w.x - dy * w.y, dx * w.y + dy * w.x);
            }
        }
        // ---- stages h=16..1 via shfl_xor ----
#pragma unroll
        for (int hs = 4; hs >= 0; --hs) {
            const int h = 1 << hs;
            float2 w = tw[h + (j & (h - 1))];
            const bool upper = (j & h) != 0;
#pragma unroll
            for (int r = 0; r < 16; ++r) {
                float ox = __shfl_xor(v[r].x, h);
                float oy = __shfl_xor(v[r].y, h);
                float sx = v[r].x + ox, sy = v[r].y + oy;
                float dx = ox - v[r].x, dy = oy - v[r].y;
                float tx = dx * w.x - dy * w.y, ty = dx * w.y + dy * w.x;
                v[r].x = upper ? tx : sx;
                v[r].y = upper ? ty : sy;
            }
        }

        // ---- epilogue: mags into registers, phase stats, histograms ----
#pragma unroll
        for (int r = 0; r < 16; ++r) {
            float mag = sqrtf(v[r].x * v[r].x + v[r].y * v[r].y);
            union { _Float16 h; unsigned short u; } cvt;
            cvt.h = (_Float16)mag;
            int ei = cgi * 16 + r;
            if (ei & 1) mgp[ei >> 1] |= ((unsigned)cvt.u) << 16;
            else        mgp[ei >> 1] = (unsigned)cvt.u;
            atomicAdd(&mh[min((unsigned)(cvt.u >> 4), (unsigned)(NBIN - 1))], 1u);
            float phv = atan2f(v[r].y, v[r].x);
            lsum += phv;
            lsq += phv * phv;
            int bin = min(max((int)floorf((phv + PI_F) / TWO_PI_F * 64.0f), 0), 63);
            atomicAdd(&ph[bin], 1u);
        }
    }

    for (int off = 32; off > 0; off >>= 1) {
        lsum += __shfl_down(lsum, off);
        lsq  += __shfl_down(lsq, off);
    }
    if ((t & 63) == 0) { red[t >> 6] = lsum; red[8 + (t >> 6)] = lsq; }
    __syncthreads();
    if (t == 0) {
        float s = 0.f, q = 0.f;
        for (int i = 0; i < 8; ++i) { s += red[i]; q += red[8 + i]; }
        atomicAdd(psum + b, s);
        atomicAdd(psumsq + b, q);
    }
    if (t < 64 && ph[t]) atomicAdd(&phist[b * 64 + t], ph[t]);
    for (int i = t; i < NBIN; i += 512)
        if (mh[i]) atomicAdd(&mhist[b * NBIN + i], mh[i]);

    // =================== grid-wide barrier ===================
    cg::this_grid().sync();

    // ---- threshold: suffix-scan the batch histogram (each block redoes) ----
    {
        unsigned s = 0;
#pragma unroll
        for (int i = 0; i < 4; ++i) s += mhist[b * NBIN + t * 4 + i];
        scanA[t] = s;
        __syncthreads();
        unsigned* src = scanA;
        unsigned* dst = scanB;
#pragma unroll
        for (int off = 1; off < 512; off <<= 1) {
            unsigned val = src[t] + ((t + off < 512) ? src[t + off] : 0u);
            dst[t] = val;
            __syncthreads();
            unsigned* tmp = src; src = dst; dst = tmp;
            __syncthreads();
        }
        // src[t] = suffix count of chunk t (bins >= 4t)
        unsigned sufNext = (t < 511) ? src[t + 1] : 0u;
        if (src[t] >= 128u && sufNext < 128u) {
            unsigned acc = sufNext;
            int tb = t * 4;
            for (int i = t * 4 + 3; i >= t * 4; --i) {
                acc += mhist[b * NBIN + i];
                if (acc >= 128u) { tb = i; break; }
            }
            seltb = tb;
        }
        __syncthreads();
    }
    const unsigned tb = (unsigned)seltb;

    // ---- append register-resident candidates ----
    float* cb = cand + b * TK_CAP;
#pragma unroll
    for (int i = 0; i < 16; ++i) {
        unsigned vv = mgp[i];
#pragma unroll
        for (int k = 0; k < 2; ++k) {
            unsigned short ub = (k == 0) ? (unsigned short)(vv & 0xFFFFu)
                                         : (unsigned short)(vv >> 16);
            if ((unsigned)(ub >> 4) >= tb) {
                unsigned p = atomicAdd(&ccnt[b], 1u);
                if (p < TK_CAP) {
                    union { unsigned short u; _Float16 h; } c2;
                    c2.u = ub;
                    cb[p] = (float)c2.h;
                }
            }
        }
    }
}

// ===========================================================================
// top-k: bitonic sort descending -> dom top-128 ; FUSED sims epilogue
// (block b owns top-128 in LDS; 64 threads compute the 64 cosine sims)
// ===========================================================================
__global__ void __launch_bounds__(1024) sort_kernel(const float* __restrict__ cand,
                                                    const unsigned* __restrict__ ccnt,
                                                    const float* __restrict__ rec,
                                                    float* __restrict__ comb,
                                                    float* __restrict__ dout) {
    __shared__ float c[TK_CAP];
    const int b = blockIdx.x, t = threadIdx.x;
    const unsigned n = min(ccnt[b], (unsigned)TK_CAP);
    int P = 256;
    while (P < (int)n) P <<= 1;                 // 256..4096
    for (int i = t; i < P; i += 1024) c[i] = (i < (int)n) ? cand[b * TK_CAP + i] : -1.0f;
    __syncthreads();
    for (int k = 2; k <= P; k <<= 1) {
        for (int j = k >> 1; j > 0; j >>= 1) {
            for (int i = t; i < P; i += 1024) {
                int ixj = i ^ j;
                if (ixj > i) {
                    float a = c[i], d = c[ixj];
                    bool up = ((i & k) == 0);
                    if (up ? (a < d) : (a > d)) { c[i] = d; c[ixj] = a; }
                }
            }
            __syncthreads();
        }
    }
    // ---- sims epilogue: top-128 are c[0..127] ----
    if (t < 64) {
        float dn = 0.f;
        for (int k = 0; k < 128; ++k) dn += c[k] * c[k];
        const float* rv = rec + t * 128;
        float rn = 0.f, dot = 0.f;
        for (int k = 0; k < 128; ++k) {
            float r = rv[k];
            rn += r * r;
            dot += c[k] * r;
        }
        float val = dot / (fmaxf(sqrtf(dn), 1e-12f) * fmaxf(sqrtf(rn), 1e-12f));
        dout[b * 64 + t] = val;
        comb[b * 1091 + t] = val;
    }
}

// ===========================================================================
// FUSED gradient + conv1 + ReLU + maxpool2 -> h1 NHWC fp16, via MFMA
// implicit GEMM. Lane owns adjacent oc pair (2m, 2m+1) -> single h2 store.
// ===========================================================================
__global__ void __launch_bounds__(256) grad_conv1_mfma(const float* __restrict__ img,
                                                       const half8* __restrict__ w1r,
                                                       const float* __restrict__ c1b,
                                                       _Float16* __restrict__ h1) {
    __shared__ float simg[36 * 37];
    __shared__ _Float16 sgrad[(34 * 36 + 1) * 2];   // [(y+1)*36+(x+1)] -> (mag,ori); +1 zero pair
    const int blk = blockIdx.x;               // b*256 + tile
    const int b = blk >> 8;
    const int tr = blk & 255;                 // 16x16 tiles of 32 pre-pool px
    const int TY = (tr >> 4) * 32, TX = (tr & 15) * 32;
    const int t = threadIdx.x;
    const float* im = img + (long long)b * 262144;

    for (int idx = t; idx < 1296; idx += 256) {
        int iy = idx / 36, ix = idx - iy * 36;
        int gy = min(max(TY - 2 + iy, 0), 511);
        int gx = min(max(TX - 2 + ix, 0), 511);
        simg[iy * 37 + ix] = im[gy * 512 + gx];
    }
    if (t == 0) { sgrad[2448] = (_Float16)0.f; sgrad[2449] = (_Float16)0.f; }
    __syncthreads();

    for (int idx = t; idx < 1156; idx += 256) {
        int ly = idx / 34, lx = idx - ly * 34;       // 0..33
        int gy = TY - 1 + ly, gx = TX - 1 + lx;
        float up = simg[ly * 37 + lx + 1];
        float dn = simg[(ly + 2) * 37 + lx + 1];
        float lf = simg[(ly + 1) * 37 + lx];
        float rt = simg[(ly + 1) * 37 + lx + 2];
        float fy = (gy <= 0 || gy >= 511) ? 1.f : 0.5f;
        float fx = (gx <= 0 || gx >= 511) ? 1.f : 0.5f;
        float gyv = (dn - up) * fy, gxv = (rt - lf) * fx;
        bool inside = ((unsigned)gy < 512u) && ((unsigned)gx < 512u);
        float mag = inside ? sqrtf(gxv * gxv + gyv * gyv) : 0.f;
        float ori = inside ? atan2f(gyv, gxv) : 0.f;
        int p = (ly * 36 + lx) * 2;
        sgrad[p] = (_Float16)mag;
        sgrad[p + 1] = (_Float16)ori;
    }
    __syncthreads();

    const int w = t >> 6, lane = t & 63;
    const int q = lane >> 4, m = lane & 15;
    const int oc0 = 2 * m;                    // adjacent pair (paired repack)
    const float bias0 = c1b[oc0], bias1 = c1b[oc0 + 1];
    half8 Bf0 = w1r[lane], Bf1 = w1r[64 + lane];
    const unsigned* gp = (const unsigned*)sgrad;
    const int ZP = 1224;                      // zero pair index

    const int sy = (m >> 1) & 1, sx = m & 1, dqx = m >> 2;

#pragma unroll 4
    for (int i = 0; i < 16; ++i) {
        const int mt = w * 16 + i;            // 0..63
        const int qy = mt >> 2, qxg = mt & 3;
        const int py = 2 * qy + sy;
        const int px = 2 * (qxg * 4 + dqx) + sx;
        const int base = py * 36 + px;

        int o0 = (q == 0) ? base      : (q == 1) ? base + 37 : (q == 2) ? base + 74 : ZP;
        int o1 = (q == 0) ? base + 1  : (q == 1) ? base + 38 : ZP;
        int o2 = (q == 0) ? base + 2  : (q == 1) ? base + 72 : ZP;
        int o3 = (q == 0) ? base + 36 : (q == 1) ? base + 73 : ZP;

        union { unsigned u[4]; half8 h; } Af;
        Af.u[0] = gp[o0]; Af.u[1] = gp[o1]; Af.u[2] = gp[o2]; Af.u[3] = gp[o3];

        floatx4 acc0 = {bias0, bias0, bias0, bias0};
        floatx4 acc1 = {bias1, bias1, bias1, bias1};
        acc0 = __builtin_amdgcn_mfma_f32_16x16x32_f16(Af.h, Bf0, acc0, 0, 0, 0);
        acc1 = __builtin_amdgcn_mfma_f32_16x16x32_f16(Af.h, Bf1, acc1, 0, 0, 0);

        float v0 = fmaxf(fmaxf(acc0[0], acc0[1]), fmaxf(acc0[2], acc0[3]));
        float v1 = fmaxf(fmaxf(acc1[0], acc1[1]), fmaxf(acc1[2], acc1[3]));
        v0 = fmaxf(v0, 0.f);
        v1 = fmaxf(v1, 0.f);

        const int PY = (TY >> 1) + qy;
        const int PX = (TX >> 1) + qxg * 4 + q;
        _Float16* dst = h1 + (((size_t)(b * 256 + PY)) * 256 + PX) * 32;
        *(h2*)(dst + oc0) = h2{(_Float16)v0, (_Float16)v1};
    }
}

// ===========================================================================
// conv2 (32->64, 3x3 SAME) + ReLU + 64x64 avg-pool partials — implicit GEMM.
// FROZEN at r11 form (60 µs).
// ===========================================================================
__global__ void __launch_bounds__(256) conv2_mfma(const _Float16* __restrict__ h1,
                                                  const _Float16* __restrict__ wrep,
                                                  const float* __restrict__ c2b,
                                                  float* __restrict__ sacc) {
    __shared__ _Float16 tile[18 * 34 * 32];     // [row][px][ic] 39,168 B
    __shared__ float lsum[64];
    const int blk = blockIdx.x;                 // b*128 + yt*8 + xt
    const int b  = blk >> 7;
    const int yt = (blk >> 3) & 15;
    const int xt = blk & 7;
    const int y0 = yt * 16, x0 = xt * 32;
    const int t = threadIdx.x;
    if (t < 64) lsum[t] = 0.f;

    for (int c = t; c < 18 * 136; c += 256) {
        int row = c / 136;
        int chunk = c - row * 136;
        int gy = y0 - 1 + row;
        int px = chunk >> 2;
        int gx = x0 - 1 + px;
        floatx4 v = {0.f, 0.f, 0.f, 0.f};
        if ((unsigned)gy < 256u && (unsigned)gx < 256u)
            v = *(const floatx4*)(h1 + (((size_t)(b * 256 + gy)) * 256 + gx) * 32 + (chunk & 3) * 8);
        *(floatx4*)(tile + (row * 34 + px) * 32 + (chunk & 3) * 8) = v;
    }
    __syncthreads();

    const int w = t >> 6, lane = t & 63;
    const int q = lane >> 4, ln15 = lane & 15;
    float bias[4];
#pragma unroll
    for (int nt = 0; nt < 4; ++nt) bias[nt] = c2b[nt * 16 + ln15];
    float partial[4] = {0.f, 0.f, 0.f, 0.f};

#pragma unroll 1
    for (int gr = 0; gr < 2; ++gr) {
        floatx4 acc[4][4];
#pragma unroll
        for (int mt = 0; mt < 4; ++mt)
#pragma unroll
            for (int nt = 0; nt < 4; ++nt)
                acc[mt][nt] = floatx4{bias[nt], bias[nt], bias[nt], bias[nt]};

        const _Float16* ab = tile + (((w * 4 + gr * 2) * 34) + ln15) * 32 + q * 8;
        const _Float16* wk = wrep + lane * 8;   // advances 2048 halfs per tap

#pragma unroll 1
        for (int ky = 0; ky < 3; ++ky) {
#pragma unroll
            for (int kx = 0; kx < 3; ++kx) {
                half8 Bf[4];
#pragma unroll
                for (int nt = 0; nt < 4; ++nt)
                    Bf[nt] = *(const half8*)(wk + (kx * 4 + nt) * 512);
#pragma unroll
                for (int mt = 0; mt < 4; ++mt) {
                    half8 Af = *(const half8*)(ab + (mt >> 1) * 1088 + (mt & 1) * 512 + kx * 32);
#pragma unroll
                    for (int nt = 0; nt < 4; ++nt)
                        acc[mt][nt] = __builtin_amdgcn_mfma_f32_16x16x32_f16(Af, Bf[nt], acc[mt][nt], 0, 0, 0);
                }
            }
            ab += 34 * 32;                      // next ky row
            wk += 3 * 2048;                     // next tap row (3 taps)
        }

#pragma unroll
        for (int mt = 0; mt < 4; ++mt)
#pragma unroll
            for (int nt = 0; nt < 4; ++nt)
#pragma unroll
                for (int rg = 0; rg < 4; ++rg)
                    partial[nt] += fmaxf(acc[mt][nt][rg], 0.f);
    }

#pragma unroll
    for (int nt = 0; nt < 4; ++nt) {
        float v = partial[nt];
        v += __shfl_xor(v, 16);
        v += __shfl_xor(v, 32);
        if (lane < 16) atomicAdd(&lsum[nt * 16 + ln15], v);
    }
    __syncthreads();
    const int cell = (yt >> 2) * 4 + (xt >> 1);
    if (t < 64) atomicAdd(&sacc[(((b << 6) + t) << 4) + cell], lsum[t]);
}

// ===========================================================================
// combined finalize: blocks 0..63 spatial, block 64 phase
// ===========================================================================
__global__ void __launch_bounds__(256) finalize_kernel(const float* __restrict__ sacc,
                                                       const float* __restrict__ psum,
                                                       const float* __restrict__ psumsq,
                                                       const unsigned* __restrict__ phist,
                                                       float* __restrict__ comb,
                                                       float* __restrict__ dout) {
    if (blockIdx.x < 64) {
        int idx = blockIdx.x * 256 + threadIdx.x;     // 16384
        int b = idx >> 10, j = idx & 1023;
        float v = sacc[idx] * (1.0f / 4096.0f);
        dout[1024 + idx] = v;
        comb[b * 1091 + 64 + j] = v;
    } else {
        int t = threadIdx.x;
        if (t < 16) {
            const float N = 262144.f;
            float s = psum[t];
            float mean = s / N;
            float var = (psumsq[t] - s * s / N) / (N - 1.f);
            float sd = sqrtf(fmaxf(var, 0.f));
            float ent = 0.f;
            for (int i = 0; i < 64; ++i) {
                float p = (float)phist[t * 64 + i] / N;
                ent -= p * logf(p + 1e-10f);
            }
            dout[17408 + t * 3 + 0] = mean;
            dout[17408 + t * 3 + 1] = sd;
            dout[17408 + t * 3 + 2] = ent;
            float* cb = comb + t * 1091 + 1088;
            cb[0] = mean; cb[1] = sd; cb[2] = ent;
        }
    }
}

// ===========================================================================
// fc1: wave per (b,o), coalesced weight-row sweep + shuffle reduce
// ===========================================================================
__global__ void __launch_bounds__(256) fc1_kernel(const float* __restrict__ comb,
                                                  const float* __restrict__ W1,
                                                  const float* __restrict__ B1,
                                                  float* __restrict__ out1) {
    const int wid = blockIdx.x * 4 + (threadIdx.x >> 6);  // 0..8191
    const int lane = threadIdx.x & 63;
    const int b = wid >> 9, o = wid & 511;
    const float* w = W1 + (size_t)o * 1091;
    const float* c = comb + b * 1091;
    float acc = 0.f;
#pragma unroll 4
    for (int i = 0; i < 17; ++i) {
        int k = i * 64 + lane;
        acc += w[k] * c[k];                     // 17*64 = 1088
    }
    if (lane < 3) acc += w[1088 + lane] * c[1088 + lane];
#pragma unroll
    for (int off = 32; off > 0; off >>= 1) acc += __shfl_down(acc, off);
    if (lane == 0) out1[b * 512 + o] = fmaxf(acc + B1[o], 0.f);
}

// ===========================================================================
// fc2: wave per (b,o)
// ===========================================================================
__global__ void __launch_bounds__(256) fc2_kernel(const float* __restrict__ out1,
                                                  const float* __restrict__ W2,
                                                  const float* __restrict__ B2,
                                                  float* __restrict__ z) {
    const int wid = blockIdx.x * 4 + (threadIdx.x >> 6);  // 0..2047
    const int lane = threadIdx.x & 63;
    const int b = wid >> 7, o = wid & 127;
    const float* w = W2 + (size_t)o * 512;
    const float* c = out1 + b * 512;
    float acc = 0.f;
#pragma unroll
    for (int i = 0; i < 8; ++i) {
        int k = i * 64 + lane;
        acc += w[k] * c[k];
    }
#pragma unroll
    for (int off = 32; off > 0; off >>= 1) acc += __shfl_down(acc, off);
    if (lane == 0) z[b * 128 + o] = acc + B2[o];
}

// ===========================================================================
// layernorm over z[16,128] -> holo
// ===========================================================================
__global__ void __launch_bounds__(128) ln_kernel(const float* __restrict__ z,
                                                 const float* __restrict__ g,
                                                 const float* __restrict__ beta,
                                                 float* __restrict__ dout) {
    __shared__ float red[4];
    const int b = blockIdx.x, t = threadIdx.x;
    float acc = z[b * 128 + t];
    float s = acc;
    for (int off = 32; off > 0; off >>= 1) s += __shfl_down(s, off);
    if ((t & 63) == 0) red[t >> 6] = s;
    __syncthreads();
    float mu = (red[0] + red[1]) * (1.0f / 128.0f);
    float d = acc - mu;
    float q = d * d;
    for (int off = 32; off > 0; off >>= 1) q += __shfl_down(q, off);
    if ((t & 63) == 0) red[2 + (t >> 6)] = q;
    __syncthreads();
    float var = (red[2] + red[3]) * (1.0f / 128.0f);
    dout[17456 + b * 128 + t] = d / sqrtf(var + 1e-5f) * g[t] + beta[t];
}

// ===========================================================================
// launcher
// ===========================================================================
extern "C" void kernel_launch(void* const* d_in, const int* in_sizes, int n_in,
                              void* d_out, int out_size, void* d_ws, size_t ws_size,
                              hipStream_t stream) {
    const float* img = (const float*)d_in[0];
    const float* rec = (const float*)d_in[1];
    const float* w1  = (const float*)d_in[2];
    const float* c1b = (const float*)d_in[3];
    const float* w2  = (const float*)d_in[4];
    const float* c2b = (const float*)d_in[5];
    const float* fw1 = (const float*)d_in[6];
    const float* fb1 = (const float*)d_in[7];
    const float* fw2 = (const float*)d_in[8];
    const float* fb2 = (const float*)d_in[9];
    const float* lng = (const float*)d_in[10];
    const float* lnb = (const float*)d_in[11];
    float* out = (float*)d_out;

    float* ws = (float*)d_ws;
    h2* rowhf       = (h2*)ws;                    // region0: 16*512*512 half2 = 16.8 MB
    _Float16* h1    = (_Float16*)(ws + OFF_BIG);  // region1: NHWC conv1 out
    float* small_  = ws + OFF_SMALL;
    float* sacc    = small_;                      // 16384
    float* psum    = small_ + 16384;              // 16
    float* psumsq  = small_ + 16400;              // 16
    unsigned* phist = (unsigned*)(small_ + 16416);// 1024
    unsigned* mhist = (unsigned*)(small_ + 17440);// NBIN*16 = 32768 (region sized 65536)
    unsigned* ccnt  = (unsigned*)(small_ + 82976);// 16    (zeroed range ends at 82992)
    float* comb    = small_ + 85056;              // 17456
    float* out1    = small_ + 102512;             // 8192
    _Float16* wrep = (_Float16*)(small_ + 110704);// 18432 f16 = 9216 dwords
    float2* twg    = (float2*)(small_ + 119920);  // 512 float2 = 1024 dwords
    float* cand    = small_ + 120944;             // 16*4096 = 65536 dwords
    float* zbuf    = cand;                        // alias (cand dead after sort)
    _Float16* w1r  = (_Float16*)(small_ + 186480);// 1024 f16 = 512 dwords

    init_kernel<<<325, 256, 0, stream>>>(sacc, twg, w2, w1, wrep, w1r);
    fft_rows2<<<4096, 256, 0, stream>>>(img, twg, rowhf);
    {
        const h2* rp = rowhf;
        const float2* tp = twg;
        void* cargs[] = { (void*)&rp, (void*)&tp, (void*)&psum, (void*)&psumsq,
                          (void*)&phist, (void*)&mhist, (void*)&cand, (void*)&ccnt };
        hipLaunchCooperativeKernel((const void*)fftcol_coop, dim3(256), dim3(512),
                                   cargs, 0, stream);
    }
    sort_kernel<<<16, 1024, 0, stream>>>(cand, ccnt, rec, comb, out);
    grad_conv1_mfma<<<4096, 256, 0, stream>>>(img, (const half8*)w1r, c1b, h1);
    conv2_mfma<<<2048, 256, 0, stream>>>(h1, wrep, c2b, sacc);
    finalize_kernel<<<65, 256, 0, stream>>>(sacc, psum, psumsq, phist, comb, out);
    fc1_kernel<<<2048, 256, 0, stream>>>(comb, fw1, fb1, out1);
    fc2_kernel<<<512, 256, 0, stream>>>(out1, fw2, fb2, zbuf);
    ln_kernel<<<16, 128, 0, stream>>>(zbuf, lng, lnb, out);
}

// Round 15
// 272.435 us; speedup vs baseline: 1.1962x; 1.1962x over previous
//
#include <hip/hip_runtime.h>
#include <hip/hip_fp16.h>
#include <math.h>

// ---------------------------------------------------------------------------
// HolographicPatternExtractor  (B=16, C=1, H=W=512)
//  outputs (flat f32): sims[16,64] | spatial[16,1024] | phase_feats[16,3] | holo[16,128]
// ---------------------------------------------------------------------------

#define PI_F 3.14159274f          // float(np.pi)
#define TWO_PI_F 6.28318548f

typedef _Float16 half8 __attribute__((ext_vector_type(8)));
typedef _Float16 h2 __attribute__((ext_vector_type(2)));
typedef float floatx4 __attribute__((ext_vector_type(4)));

// ---- workspace layout (dword offsets) ----
#define OFF_BIG   8388608
#define OFF_SMALL 25165824
#define NBIN 2048                 // magnitude histogram bins (fp16 bits>>4)

// ===========================================================================
// combined init: zero accumulators + twiddle table + weight repacks
// ===========================================================================
__global__ void __launch_bounds__(256) init_kernel(float* __restrict__ zp,
                                                   float2* __restrict__ tw,
                                                   const float* __restrict__ w2,
                                                   const float* __restrict__ w1,
                                                   _Float16* __restrict__ wrep,
                                                   _Float16* __restrict__ w1r) {
    int idx = blockIdx.x * 256 + threadIdx.x;
    if (idx < 82992) zp[idx] = 0.0f;
    if (idx < 512) {
        if (idx == 0) tw[0] = make_float2(1.f, 0.f);
        else {
            int h = 31 - __clz(idx);
            int H = 1 << h;
            float sn, cs;
            sincosf(-PI_F * (float)(idx - H) / (float)H, &sn, &cs);
            tw[idx] = make_float2(cs, sn);
        }
    }
    if (idx < 18432) {            // conv2 MFMA B-fragment
        int j = idx & 7;
        int lane = (idx >> 3) & 63;
        int nt = (idx >> 9) & 3;
        int tap = idx >> 11;
        int oc = nt * 16 + (lane & 15);
        int ic = (lane >> 4) * 8 + j;
        wrep[idx] = (_Float16)w2[(oc * 32 + ic) * 9 + tap];
    }
    if (idx < 1024) {             // conv1 MFMA B-fragment: [nt][lane][j]
        // PAIRED oc: nt=0 -> even oc (2m), nt=1 -> odd (2m+1) -> one h2 store
        int j = idx & 7;
        int lane = (idx >> 3) & 63;
        int nt = idx >> 9;
        int oc = 2 * (lane & 15) + nt;
        int k = (lane >> 4) * 8 + j;      // k = 2*tap + ch, pad >=18 with 0
        _Float16 v = (_Float16)0.f;
        if (k < 18) {
            int tap = k >> 1, ch = k & 1;
            v = (_Float16)w1[oc * 18 + ch * 9 + tap];
        }
        w1r[idx] = v;
    }
}

// ===========================================================================
// FFT row pass, REAL-PAIR packed: rows (2y, 2y+1) as one complex 512-pt DIF
// FFT; Hermitian untangle; spectra stored as half2 (fp16 re/im).
// ===========================================================================
__global__ void __launch_bounds__(256) fft_rows2(const float* __restrict__ img,
                                                 const float2* __restrict__ twg,
                                                 h2* __restrict__ rowhf) {
    __shared__ float2 s[512];
    __shared__ float2 tw[512];
    const int t = threadIdx.x;
    const long long rbase = (long long)blockIdx.x * 1024;   // row-pair base elem
    const float* x0 = img + rbase;
    const float* x1 = x0 + 512;

    for (int i = t; i < 512; i += 256) tw[i] = twg[i];
    for (int i = t; i < 512; i += 256) s[i] = make_float2(x0[i], x1[i]);
    __syncthreads();
#pragma unroll
    for (int st = 9; st >= 1; --st) {
        const int half = 1 << (st - 1);
        const int pos = t & (half - 1);
        const int grp = t >> (st - 1);
        const int i1 = (grp << st) + pos;
        const int i2 = i1 + half;
        float2 w = tw[half + pos];
        float2 a = s[i1], b = s[i2];
        float dx = a.x - b.x, dy = a.y - b.y;
        s[i1] = make_float2(a.x + b.x, a.y + b.y);
        s[i2] = make_float2(dx * w.x - dy * w.y, dx * w.y + dy * w.x);
        __syncthreads();
    }
    // untangle: X0(k)=(Z(k)+conj(Z(-k)))/2, X1(k)=-i(Z(k)-conj(Z(-k)))/2
    for (int i = t; i < 512; i += 256) {
        int k = __brev((unsigned)i) >> 23;
        int kp = (512 - k) & 511;
        int jp = __brev((unsigned)kp) >> 23;
        float2 Z = s[i], Zp = s[jp];
        rowhf[rbase + i]       = h2{(_Float16)(0.5f * (Z.x + Zp.x)),
                                    (_Float16)(0.5f * (Z.y - Zp.y))};
        rowhf[rbase + 512 + i] = h2{(_Float16)(0.5f * (Z.y + Zp.y)),
                                    (_Float16)(-0.5f * (Z.x - Zp.x))};
    }
}

// ===========================================================================
// FFT column pass — REGISTER FFT (r13 form: 3 blocks/CU, NOT cooperative —
// the 1-block/CU cooperative fusion regressed 78 µs from occupancy loss).
// 16 columns/block, 512 threads. Fused magnitude (fp16, transposed), phase
// stats, fp16-bit magnitude histogram.
// ===========================================================================
#define FCOLS 16
__global__ void __launch_bounds__(512) fft_cols(const h2* __restrict__ rowhf,
                                                const float2* __restrict__ twg,
                                                _Float16* __restrict__ magT,
                                                float* __restrict__ psum,
                                                float* __restrict__ psumsq,
                                                unsigned* __restrict__ phist,
                                                unsigned* __restrict__ mhist) {
    __shared__ h2 sh[FCOLS * 512];              // 32 KB  [c][y]
    __shared__ float2 tw[512];                  // 4 KB
    __shared__ unsigned ph[64];
    __shared__ unsigned mh[NBIN];               // 8 KB
    __shared__ float red[16];
    const int t = threadIdx.x;
    const int b = blockIdx.x >> 5;              // 32 blocks per batch
    const int x0 = (blockIdx.x & 31) * FCOLS;

    for (int i = t; i < 512; i += 512) tw[i] = twg[i];
    if (t < 64) ph[t] = 0u;
    for (int i = t; i < NBIN; i += 512) mh[i] = 0u;
    for (int idx = t; idx < FCOLS * 512; idx += 512) {
        int y = idx >> 4, c = idx & 15;
        sh[c * 512 + y] = rowhf[((size_t)(b * 512 + y)) * 512 + x0 + c];
    }
    __syncthreads();

    const int c = t >> 5;                       // 0..15
    const int j = t & 31;
    float2 v[16];
#pragma unroll
    for (int r = 0; r < 16; ++r) {
        h2 hv = sh[c * 512 + j + 32 * r];
        v[r] = make_float2((float)hv[0], (float)hv[1]);
    }
    // ---- stage h=256 ----
#pragma unroll
    for (int r = 0; r < 8; ++r) {
        float2 w = tw[256 + j + 32 * r];
        float2 a = v[r], bb = v[r + 8];
        float dx = a.x - bb.x, dy = a.y - bb.y;
        v[r]     = make_float2(a.x + bb.x, a.y + bb.y);
        v[r + 8] = make_float2(dx * w.x - dy * w.y, dx * w.y + dy * w.x);
    }
    // ---- stage h=128 ----
#pragma unroll
    for (int g = 0; g < 2; ++g)
#pragma unroll
        for (int rr = 0; rr < 4; ++rr) {
            int r = g * 8 + rr;
            float2 w = tw[128 + j + 32 * rr];
            float2 a = v[r], bb = v[r + 4];
            float dx = a.x - bb.x, dy = a.y - bb.y;
            v[r]     = make_float2(a.x + bb.x, a.y + bb.y);
            v[r + 4] = make_float2(dx * w.x - dy * w.y, dx * w.y + dy * w.x);
        }
    // ---- stage h=64 ----
#pragma unroll
    for (int g = 0; g < 4; ++g)
#pragma unroll
        for (int rr = 0; rr < 2; ++rr) {
            int r = g * 4 + rr;
            float2 w = tw[64 + j + 32 * rr];
            float2 a = v[r], bb = v[r + 2];
            float dx = a.x - bb.x, dy = a.y - bb.y;
            v[r]     = make_float2(a.x + bb.x, a.y + bb.y);
            v[r + 2] = make_float2(dx * w.x - dy * w.y, dx * w.y + dy * w.x);
        }
    // ---- stage h=32 ----
    {
        float2 w = tw[32 + j];
#pragma unroll
        for (int g = 0; g < 8; ++g) {
            int r = g * 2;
            float2 a = v[r], bb = v[r + 1];
            float dx = a.x - bb.x, dy = a.y - bb.y;
            v[r]     = make_float2(a.x + bb.x, a.y + bb.y);
            v[r + 1] = make_float2(dx * w.x - dy * w.y, dx * w.y + dy * w.x);
        }
    }
    // ---- stages h=16..1: shuffle across lanes ----
#pragma unroll
    for (int hs = 4; hs >= 0; --hs) {
        const int h = 1 << hs;
        float2 w = tw[h + (j & (h - 1))];
        const bool upper = (j & h) != 0;
#pragma unroll
        for (int r = 0; r < 16; ++r) {
            float ox = __shfl_xor(v[r].x, h);
            float oy = __shfl_xor(v[r].y, h);
            float sx = v[r].x + ox, sy = v[r].y + oy;
            float dx = ox - v[r].x, dy = oy - v[r].y;
            float tx = dx * w.x - dy * w.y, ty = dx * w.y + dy * w.x;
            v[r].x = upper ? tx : sx;
            v[r].y = upper ? ty : sy;
        }
    }

    // ---- epilogue ----
    float lsum = 0.f, lsq = 0.f;
    _Float16* mcol = magT + ((size_t)(b * 512 + x0 + c)) * 512;
#pragma unroll
    for (int r = 0; r < 16; ++r) {
        float mag = sqrtf(v[r].x * v[r].x + v[r].y * v[r].y);
        union { _Float16 h; unsigned short u; } cvt;
        cvt.h = (_Float16)mag;
        mcol[j + 32 * r] = cvt.h;
        atomicAdd(&mh[min((unsigned)(cvt.u >> 4), (unsigned)(NBIN - 1))], 1u);
        float phv = atan2f(v[r].y, v[r].x);
        lsum += phv;
        lsq += phv * phv;
        int bin = min(max((int)floorf((phv + PI_F) / TWO_PI_F * 64.0f), 0), 63);
        atomicAdd(&ph[bin], 1u);
    }
    for (int off = 32; off > 0; off >>= 1) {
        lsum += __shfl_down(lsum, off);
        lsq  += __shfl_down(lsq, off);
    }
    if ((t & 63) == 0) { red[t >> 6] = lsum; red[8 + (t >> 6)] = lsq; }
    __syncthreads();
    if (t == 0) {
        float s = 0.f, q = 0.f;
        for (int i = 0; i < 8; ++i) { s += red[i]; q += red[8 + i]; }
        atomicAdd(psum + b, s);
        atomicAdd(psumsq + b, q);
    }
    if (t < 64 && ph[t]) atomicAdd(&phist[b * 64 + t], ph[t]);
    for (int i = t; i < NBIN; i += 512)
        if (mh[i]) atomicAdd(&mhist[b * NBIN + i], mh[i]);
}

// ===========================================================================
// top-k: threshold bin from histogram suffix-count
// ===========================================================================
__global__ void __launch_bounds__(256) thresh_kernel(const unsigned* __restrict__ mhist,
                                                     int* __restrict__ selbin) {
    __shared__ unsigned csum[256];
    const int b = blockIdx.x, t = threadIdx.x;
    unsigned s = 0;
    for (int i = 0; i < NBIN / 256; ++i) s += mhist[b * NBIN + t * (NBIN / 256) + i];
    csum[t] = s;
    __syncthreads();
    if (t == 0) {
        unsigned acc = 0; int chunk = 0;
        for (int i = 255; i >= 0; --i) {
            acc += csum[i];
            if (acc >= 128u) { chunk = i; break; }
        }
        unsigned acc2 = acc - csum[chunk];      // count strictly above chunk
        int tb = chunk * (NBIN / 256);
        for (int i = chunk * (NBIN / 256) + (NBIN / 256) - 1; i >= chunk * (NBIN / 256); --i) {
            acc2 += mhist[b * NBIN + i];
            if (acc2 >= 128u) { tb = i; break; }
        }
        selbin[b] = tb;
    }
}

// ===========================================================================
// top-k: parallel candidate collection (256 blocks, fp16 magT, uint4 loads)
// ===========================================================================
#define TK_CAP 4096
__global__ void __launch_bounds__(256) collect_kernel(const _Float16* __restrict__ magT,
                                                      const int* __restrict__ selbin,
                                                      float* __restrict__ cand,
                                                      unsigned* __restrict__ ccnt) {
    const int blk = blockIdx.x;
    const int b = blk >> 4, chunk = blk & 15;
    const unsigned tb = (unsigned)selbin[b];
    const uint4* m = (const uint4*)(magT + (size_t)b * 262144 + chunk * 16384);
    float* cb = cand + b * TK_CAP;
    for (int i = threadIdx.x; i < 2048; i += 256) {
        uint4 v4 = m[i];
        unsigned vv[4] = {v4.x, v4.y, v4.z, v4.w};
#pragma unroll
        for (int j = 0; j < 4; ++j) {
#pragma unroll
            for (int k = 0; k < 2; ++k) {
                unsigned short ub = (k == 0) ? (unsigned short)(vv[j] & 0xFFFFu)
                                             : (unsigned short)(vv[j] >> 16);
                if ((unsigned)(ub >> 4) >= tb) {
                    unsigned p = atomicAdd(&ccnt[b], 1u);
                    if (p < TK_CAP) {
                        union { unsigned short u; _Float16 h; } c2;
                        c2.u = ub;
                        cb[p] = (float)c2.h;
                    }
                }
            }
        }
    }
}

// ===========================================================================
// top-k: bitonic sort descending -> top-128 ; FUSED sims epilogue
// (block b owns top-128 in LDS; 64 threads compute the 64 cosine sims)
// ===========================================================================
__global__ void __launch_bounds__(1024) sort_kernel(const float* __restrict__ cand,
                                                    const unsigned* __restrict__ ccnt,
                                                    const float* __restrict__ rec,
                                                    float* __restrict__ comb,
                                                    float* __restrict__ dout) {
    __shared__ float c[TK_CAP];
    const int b = blockIdx.x, t = threadIdx.x;
    const unsigned n = min(ccnt[b], (unsigned)TK_CAP);
    int P = 256;
    while (P < (int)n) P <<= 1;                 // 256..4096
    for (int i = t; i < P; i += 1024) c[i] = (i < (int)n) ? cand[b * TK_CAP + i] : -1.0f;
    __syncthreads();
    for (int k = 2; k <= P; k <<= 1) {
        for (int j = k >> 1; j > 0; j >>= 1) {
            for (int i = t; i < P; i += 1024) {
                int ixj = i ^ j;
                if (ixj > i) {
                    float a = c[i], d = c[ixj];
                    bool up = ((i & k) == 0);
                    if (up ? (a < d) : (a > d)) { c[i] = d; c[ixj] = a; }
                }
            }
            __syncthreads();
        }
    }
    // ---- sims epilogue: top-128 are c[0..127] ----
    if (t < 64) {
        float dn = 0.f;
        for (int k = 0; k < 128; ++k) dn += c[k] * c[k];
        const float* rv = rec + t * 128;
        float rn = 0.f, dot = 0.f;
        for (int k = 0; k < 128; ++k) {
            float r = rv[k];
            rn += r * r;
            dot += c[k] * r;
        }
        float val = dot / (fmaxf(sqrtf(dn), 1e-12f) * fmaxf(sqrtf(rn), 1e-12f));
        dout[b * 64 + t] = val;
        comb[b * 1091 + t] = val;
    }
}

// ===========================================================================
// FUSED gradient + conv1 + ReLU + maxpool2 -> h1 NHWC fp16, via MFMA
// implicit GEMM. Lane owns adjacent oc pair (2m, 2m+1) -> single h2 store.
// ===========================================================================
__global__ void __launch_bounds__(256) grad_conv1_mfma(const float* __restrict__ img,
                                                       const half8* __restrict__ w1r,
                                                       const float* __restrict__ c1b,
                                                       _Float16* __restrict__ h1) {
    __shared__ float simg[36 * 37];
    __shared__ _Float16 sgrad[(34 * 36 + 1) * 2];   // [(y+1)*36+(x+1)] -> (mag,ori); +1 zero pair
    const int blk = blockIdx.x;               // b*256 + tile
    const int b = blk >> 8;
    const int tr = blk & 255;                 // 16x16 tiles of 32 pre-pool px
    const int TY = (tr >> 4) * 32, TX = (tr & 15) * 32;
    const int t = threadIdx.x;
    const float* im = img + (long long)b * 262144;

    for (int idx = t; idx < 1296; idx += 256) {
        int iy = idx / 36, ix = idx - iy * 36;
        int gy = min(max(TY - 2 + iy, 0), 511);
        int gx = min(max(TX - 2 + ix, 0), 511);
        simg[iy * 37 + ix] = im[gy * 512 + gx];
    }
    if (t == 0) { sgrad[2448] = (_Float16)0.f; sgrad[2449] = (_Float16)0.f; }
    __syncthreads();

    for (int idx = t; idx < 1156; idx += 256) {
        int ly = idx / 34, lx = idx - ly * 34;       // 0..33
        int gy = TY - 1 + ly, gx = TX - 1 + lx;
        float up = simg[ly * 37 + lx + 1];
        float dn = simg[(ly + 2) * 37 + lx + 1];
        float lf = simg[(ly + 1) * 37 + lx];
        float rt = simg[(ly + 1) * 37 + lx + 2];
        float fy = (gy <= 0 || gy >= 511) ? 1.f : 0.5f;
        float fx = (gx <= 0 || gx >= 511) ? 1.f : 0.5f;
        float gyv = (dn - up) * fy, gxv = (rt - lf) * fx;
        bool inside = ((unsigned)gy < 512u) && ((unsigned)gx < 512u);
        float mag = inside ? sqrtf(gxv * gxv + gyv * gyv) : 0.f;
        float ori = inside ? atan2f(gyv, gxv) : 0.f;
        int p = (ly * 36 + lx) * 2;
        sgrad[p] = (_Float16)mag;
        sgrad[p + 1] = (_Float16)ori;
    }
    __syncthreads();

    const int w = t >> 6, lane = t & 63;
    const int q = lane >> 4, m = lane & 15;
    const int oc0 = 2 * m;                    // adjacent pair (paired repack)
    const float bias0 = c1b[oc0], bias1 = c1b[oc0 + 1];
    half8 Bf0 = w1r[lane], Bf1 = w1r[64 + lane];
    const unsigned* gp = (const unsigned*)sgrad;
    const int ZP = 1224;                      // zero pair index

    const int sy = (m >> 1) & 1, sx = m & 1, dqx = m >> 2;

#pragma unroll 4
    for (int i = 0; i < 16; ++i) {
        const int mt = w * 16 + i;            // 0..63
        const int qy = mt >> 2, qxg = mt & 3;
        const int py = 2 * qy + sy;
        const int px = 2 * (qxg * 4 + dqx) + sx;
        const int base = py * 36 + px;

        int o0 = (q == 0) ? base      : (q == 1) ? base + 37 : (q == 2) ? base + 74 : ZP;
        int o1 = (q == 0) ? base + 1  : (q == 1) ? base + 38 : ZP;
        int o2 = (q == 0) ? base + 2  : (q == 1) ? base + 72 : ZP;
        int o3 = (q == 0) ? base + 36 : (q == 1) ? base + 73 : ZP;

        union { unsigned u[4]; half8 h; } Af;
        Af.u[0] = gp[o0]; Af.u[1] = gp[o1]; Af.u[2] = gp[o2]; Af.u[3] = gp[o3];

        floatx4 acc0 = {bias0, bias0, bias0, bias0};
        floatx4 acc1 = {bias1, bias1, bias1, bias1};
        acc0 = __builtin_amdgcn_mfma_f32_16x16x32_f16(Af.h, Bf0, acc0, 0, 0, 0);
        acc1 = __builtin_amdgcn_mfma_f32_16x16x32_f16(Af.h, Bf1, acc1, 0, 0, 0);

        float v0 = fmaxf(fmaxf(acc0[0], acc0[1]), fmaxf(acc0[2], acc0[3]));
        float v1 = fmaxf(fmaxf(acc1[0], acc1[1]), fmaxf(acc1[2], acc1[3]));
        v0 = fmaxf(v0, 0.f);
        v1 = fmaxf(v1, 0.f);

        const int PY = (TY >> 1) + qy;
        const int PX = (TX >> 1) + qxg * 4 + q;
        _Float16* dst = h1 + (((size_t)(b * 256 + PY)) * 256 + PX) * 32;
        *(h2*)(dst + oc0) = h2{(_Float16)v0, (_Float16)v1};
    }
}

// ===========================================================================
// conv2 (32->64, 3x3 SAME) + ReLU + 64x64 avg-pool partials — implicit GEMM.
// FROZEN at r11 form (60 µs).
// ===========================================================================
__global__ void __launch_bounds__(256) conv2_mfma(const _Float16* __restrict__ h1,
                                                  const _Float16* __restrict__ wrep,
                                                  const float* __restrict__ c2b,
                                                  float* __restrict__ sacc) {
    __shared__ _Float16 tile[18 * 34 * 32];     // [row][px][ic] 39,168 B
    __shared__ float lsum[64];
    const int blk = blockIdx.x;                 // b*128 + yt*8 + xt
    const int b  = blk >> 7;
    const int yt = (blk >> 3) & 15;
    const int xt = blk & 7;
    const int y0 = yt * 16, x0 = xt * 32;
    const int t = threadIdx.x;
    if (t < 64) lsum[t] = 0.f;

    for (int c = t; c < 18 * 136; c += 256) {
        int row = c / 136;
        int chunk = c - row * 136;
        int gy = y0 - 1 + row;
        int px = chunk >> 2;
        int gx = x0 - 1 + px;
        floatx4 v = {0.f, 0.f, 0.f, 0.f};
        if ((unsigned)gy < 256u && (unsigned)gx < 256u)
            v = *(const floatx4*)(h1 + (((size_t)(b * 256 + gy)) * 256 + gx) * 32 + (chunk & 3) * 8);
        *(floatx4*)(tile + (row * 34 + px) * 32 + (chunk & 3) * 8) = v;
    }
    __syncthreads();

    const int w = t >> 6, lane = t & 63;
    const int q = lane >> 4, ln15 = lane & 15;
    float bias[4];
#pragma unroll
    for (int nt = 0; nt < 4; ++nt) bias[nt] = c2b[nt * 16 + ln15];
    float partial[4] = {0.f, 0.f, 0.f, 0.f};

#pragma unroll 1
    for (int gr = 0; gr < 2; ++gr) {
        floatx4 acc[4][4];
#pragma unroll
        for (int mt = 0; mt < 4; ++mt)
#pragma unroll
            for (int nt = 0; nt < 4; ++nt)
                acc[mt][nt] = floatx4{bias[nt], bias[nt], bias[nt], bias[nt]};

        const _Float16* ab = tile + (((w * 4 + gr * 2) * 34) + ln15) * 32 + q * 8;
        const _Float16* wk = wrep + lane * 8;   // advances 2048 halfs per tap

#pragma unroll 1
        for (int ky = 0; ky < 3; ++ky) {
#pragma unroll
            for (int kx = 0; kx < 3; ++kx) {
                half8 Bf[4];
#pragma unroll
                for (int nt = 0; nt < 4; ++nt)
                    Bf[nt] = *(const half8*)(wk + (kx * 4 + nt) * 512);
#pragma unroll
                for (int mt = 0; mt < 4; ++mt) {
                    half8 Af = *(const half8*)(ab + (mt >> 1) * 1088 + (mt & 1) * 512 + kx * 32);
#pragma unroll
                    for (int nt = 0; nt < 4; ++nt)
                        acc[mt][nt] = __builtin_amdgcn_mfma_f32_16x16x32_f16(Af, Bf[nt], acc[mt][nt], 0, 0, 0);
                }
            }
            ab += 34 * 32;                      // next ky row
            wk += 3 * 2048;                     // next tap row (3 taps)
        }

#pragma unroll
        for (int mt = 0; mt < 4; ++mt)
#pragma unroll
            for (int nt = 0; nt < 4; ++nt)
#pragma unroll
                for (int rg = 0; rg < 4; ++rg)
                    partial[nt] += fmaxf(acc[mt][nt][rg], 0.f);
    }

#pragma unroll
    for (int nt = 0; nt < 4; ++nt) {
        float v = partial[nt];
        v += __shfl_xor(v, 16);
        v += __shfl_xor(v, 32);
        if (lane < 16) atomicAdd(&lsum[nt * 16 + ln15], v);
    }
    __syncthreads();
    const int cell = (yt >> 2) * 4 + (xt >> 1);
    if (t < 64) atomicAdd(&sacc[(((b << 6) + t) << 4) + cell], lsum[t]);
}

// ===========================================================================
// combined finalize: blocks 0..63 spatial, block 64 phase
// ===========================================================================
__global__ void __launch_bounds__(256) finalize_kernel(const float* __restrict__ sacc,
                                                       const float* __restrict__ psum,
                                                       const float* __restrict__ psumsq,
                                                       const unsigned* __restrict__ phist,
                                                       float* __restrict__ comb,
                                                       float* __restrict__ dout) {
    if (blockIdx.x < 64) {
        int idx = blockIdx.x * 256 + threadIdx.x;     // 16384
        int b = idx >> 10, j = idx & 1023;
        float v = sacc[idx] * (1.0f / 4096.0f);
        dout[1024 + idx] = v;
        comb[b * 1091 + 64 + j] = v;
    } else {
        int t = threadIdx.x;
        if (t < 16) {
            const float N = 262144.f;
            float s = psum[t];
            float mean = s / N;
            float var = (psumsq[t] - s * s / N) / (N - 1.f);
            float sd = sqrtf(fmaxf(var, 0.f));
            float ent = 0.f;
            for (int i = 0; i < 64; ++i) {
                float p = (float)phist[t * 64 + i] / N;
                ent -= p * logf(p + 1e-10f);
            }
            dout[17408 + t * 3 + 0] = mean;
            dout[17408 + t * 3 + 1] = sd;
            dout[17408 + t * 3 + 2] = ent;
            float* cb = comb + t * 1091 + 1088;
            cb[0] = mean; cb[1] = sd; cb[2] = ent;
        }
    }
}

// ===========================================================================
// fc1: wave per (b,o), coalesced weight-row sweep + shuffle reduce
// ===========================================================================
__global__ void __launch_bounds__(256) fc1_kernel(const float* __restrict__ comb,
                                                  const float* __restrict__ W1,
                                                  const float* __restrict__ B1,
                                                  float* __restrict__ out1) {
    const int wid = blockIdx.x * 4 + (threadIdx.x >> 6);  // 0..8191
    const int lane = threadIdx.x & 63;
    const int b = wid >> 9, o = wid & 511;
    const float* w = W1 + (size_t)o * 1091;
    const float* c = comb + b * 1091;
    float acc = 0.f;
#pragma unroll 4
    for (int i = 0; i < 17; ++i) {
        int k = i * 64 + lane;
        acc += w[k] * c[k];                     // 17*64 = 1088
    }
    if (lane < 3) acc += w[1088 + lane] * c[1088 + lane];
#pragma unroll
    for (int off = 32; off > 0; off >>= 1) acc += __shfl_down(acc, off);
    if (lane == 0) out1[b * 512 + o] = fmaxf(acc + B1[o], 0.f);
}

// ===========================================================================
// fc2: wave per (b,o)
// ===========================================================================
__global__ void __launch_bounds__(256) fc2_kernel(const float* __restrict__ out1,
                                                  const float* __restrict__ W2,
                                                  const float* __restrict__ B2,
                                                  float* __restrict__ z) {
    const int wid = blockIdx.x * 4 + (threadIdx.x >> 6);  // 0..2047
    const int lane = threadIdx.x & 63;
    const int b = wid >> 7, o = wid & 127;
    const float* w = W2 + (size_t)o * 512;
    const float* c = out1 + b * 512;
    float acc = 0.f;
#pragma unroll
    for (int i = 0; i < 8; ++i) {
        int k = i * 64 + lane;
        acc += w[k] * c[k];
    }
#pragma unroll
    for (int off = 32; off > 0; off >>= 1) acc += __shfl_down(acc, off);
    if (lane == 0) z[b * 128 + o] = acc + B2[o];
}

// ===========================================================================
// layernorm over z[16,128] -> holo
// ===========================================================================
__global__ void __launch_bounds__(128) ln_kernel(const float* __restrict__ z,
                                                 const float* __restrict__ g,
                                                 const float* __restrict__ beta,
                                                 float* __restrict__ dout) {
    __shared__ float red[4];
    const int b = blockIdx.x, t = threadIdx.x;
    float acc = z[b * 128 + t];
    float s = acc;
    for (int off = 32; off > 0; off >>= 1) s += __shfl_down(s, off);
    if ((t & 63) == 0) red[t >> 6] = s;
    __syncthreads();
    float mu = (red[0] + red[1]) * (1.0f / 128.0f);
    float d = acc - mu;
    float q = d * d;
    for (int off = 32; off > 0; off >>= 1) q += __shfl_down(q, off);
    if ((t & 63) == 0) red[2 + (t >> 6)] = q;
    __syncthreads();
    float var = (red[2] + red[3]) * (1.0f / 128.0f);
    dout[17456 + b * 128 + t] = d / sqrtf(var + 1e-5f) * g[t] + beta[t];
}

// ===========================================================================
// launcher
// ===========================================================================
extern "C" void kernel_launch(void* const* d_in, const int* in_sizes, int n_in,
                              void* d_out, int out_size, void* d_ws, size_t ws_size,
                              hipStream_t stream) {
    const float* img = (const float*)d_in[0];
    const float* rec = (const float*)d_in[1];
    const float* w1  = (const float*)d_in[2];
    const float* c1b = (const float*)d_in[3];
    const float* w2  = (const float*)d_in[4];
    const float* c2b = (const float*)d_in[5];
    const float* fw1 = (const float*)d_in[6];
    const float* fb1 = (const float*)d_in[7];
    const float* fw2 = (const float*)d_in[8];
    const float* fb2 = (const float*)d_in[9];
    const float* lng = (const float*)d_in[10];
    const float* lnb = (const float*)d_in[11];
    float* out = (float*)d_out;

    float* ws = (float*)d_ws;
    h2* rowhf       = (h2*)ws;                    // region0: 16*512*512 half2 = 16.8 MB
    _Float16* magT  = (_Float16*)(ws + OFF_BIG);  // region1: fp16 mags 33.5 MB
    _Float16* h1    = (_Float16*)(ws + OFF_BIG);  // alias (magT dead after collect) NHWC
    float* small_  = ws + OFF_SMALL;
    float* sacc    = small_;                      // 16384
    float* psum    = small_ + 16384;              // 16
    float* psumsq  = small_ + 16400;              // 16
    unsigned* phist = (unsigned*)(small_ + 16416);// 1024
    unsigned* mhist = (unsigned*)(small_ + 17440);// NBIN*16 = 32768 (region sized 65536)
    unsigned* ccnt  = (unsigned*)(small_ + 82976);// 16    (zeroed range ends at 82992)
    int* selbin    = (int*)(small_ + 82992);      // 16
    float* comb    = small_ + 85056;              // 17456
    float* out1    = small_ + 102512;             // 8192
    _Float16* wrep = (_Float16*)(small_ + 110704);// 18432 f16 = 9216 dwords
    float2* twg    = (float2*)(small_ + 119920);  // 512 float2 = 1024 dwords
    float* cand    = small_ + 120944;             // 16*4096 = 65536 dwords
    float* zbuf    = cand;                        // alias (cand dead after sort)
    _Float16* w1r  = (_Float16*)(small_ + 186480);// 1024 f16 = 512 dwords

    init_kernel<<<325, 256, 0, stream>>>(sacc, twg, w2, w1, wrep, w1r);
    fft_rows2<<<4096, 256, 0, stream>>>(img, twg, rowhf);
    fft_cols<<<512, 512, 0, stream>>>(rowhf, twg, magT, psum, psumsq, phist, mhist);
    thresh_kernel<<<16, 256, 0, stream>>>(mhist, selbin);
    collect_kernel<<<256, 256, 0, stream>>>(magT, selbin, cand, ccnt);
    sort_kernel<<<16, 1024, 0, stream>>>(cand, ccnt, rec, comb, out);
    grad_conv1_mfma<<<4096, 256, 0, stream>>>(img, (const half8*)w1r, c1b, h1);
    conv2_mfma<<<2048, 256, 0, stream>>>(h1, wrep, c2b, sacc);
    finalize_kernel<<<65, 256, 0, stream>>>(sacc, psum, psumsq, phist, comb, out);
    fc1_kernel<<<2048, 256, 0, stream>>>(comb, fw1, fb1, out1);
    fc2_kernel<<<512, 256, 0, stream>>>(out1, fw2, fb2, zbuf);
    ln_kernel<<<16, 128, 0, stream>>>(zbuf, lng, lnb, out);
}

// Round 16
// 268.058 us; speedup vs baseline: 1.2157x; 1.0163x over previous
//
#include <hip/hip_runtime.h>
#include <hip/hip_fp16.h>
#include <math.h>

// ---------------------------------------------------------------------------
// HolographicPatternExtractor  (B=16, C=1, H=W=512)
//  outputs (flat f32): sims[16,64] | spatial[16,1024] | phase_feats[16,3] | holo[16,128]
// ---------------------------------------------------------------------------

#define PI_F 3.14159274f          // float(np.pi)
#define TWO_PI_F 6.28318548f

typedef _Float16 half8 __attribute__((ext_vector_type(8)));
typedef _Float16 h2 __attribute__((ext_vector_type(2)));
typedef float floatx4 __attribute__((ext_vector_type(4)));

// ---- workspace layout (dword offsets) ----
#define OFF_BIG   8388608
#define OFF_SMALL 25165824
#define NBIN 2048                 // magnitude histogram bins (fp16 bits>>4)

// ===========================================================================
// combined init: zero accumulators + twiddle table + weight repacks
// ===========================================================================
__global__ void __launch_bounds__(256) init_kernel(float* __restrict__ zp,
                                                   float2* __restrict__ tw,
                                                   const float* __restrict__ w2,
                                                   const float* __restrict__ w1,
                                                   _Float16* __restrict__ wrep,
                                                   _Float16* __restrict__ w1r) {
    int idx = blockIdx.x * 256 + threadIdx.x;
    if (idx < 82992) zp[idx] = 0.0f;
    if (idx < 512) {
        if (idx == 0) tw[0] = make_float2(1.f, 0.f);
        else {
            int h = 31 - __clz(idx);
            int H = 1 << h;
            float sn, cs;
            sincosf(-PI_F * (float)(idx - H) / (float)H, &sn, &cs);
            tw[idx] = make_float2(cs, sn);
        }
    }
    if (idx < 18432) {            // conv2 MFMA B-fragment
        int j = idx & 7;
        int lane = (idx >> 3) & 63;
        int nt = (idx >> 9) & 3;
        int tap = idx >> 11;
        int oc = nt * 16 + (lane & 15);
        int ic = (lane >> 4) * 8 + j;
        wrep[idx] = (_Float16)w2[(oc * 32 + ic) * 9 + tap];
    }
    if (idx < 1024) {             // conv1 MFMA B-fragment: [nt][lane][j]
        // PAIRED oc: nt=0 -> even oc (2m), nt=1 -> odd (2m+1) -> one h2 store
        int j = idx & 7;
        int lane = (idx >> 3) & 63;
        int nt = idx >> 9;
        int oc = 2 * (lane & 15) + nt;
        int k = (lane >> 4) * 8 + j;      // k = 2*tap + ch, pad >=18 with 0
        _Float16 v = (_Float16)0.f;
        if (k < 18) {
            int tap = k >> 1, ch = k & 1;
            v = (_Float16)w1[oc * 18 + ch * 9 + tap];
        }
        w1r[idx] = v;
    }
}

// ===========================================================================
// FFT row pass — REGISTER FFT, REAL-PAIR packed (rows 2y,2y+1 as one complex
// 512-pt DIF FFT). 256 threads = 8 FFT units x 32 lanes; thread j holds 16
// elements y=j+32r loaded straight from global (stride-32 => per-lane
// consecutive, coalesced). Stages h=256..32 in-register, h=16..1 shfl_xor
// (two FFTs/wave, masks <=16 stay in 32-lane halves). LDS used ONCE: stage
// final Z so the Hermitian untangle can fetch bit-reversed partner Z[jp].
// Replaces the 9-barrier LDS-butterfly version (the r12->r13 fft_cols win).
// ===========================================================================
__global__ void __launch_bounds__(256) fft_rows2(const float* __restrict__ img,
                                                 const float2* __restrict__ twg,
                                                 h2* __restrict__ rowhf) {
    __shared__ float2 sz[8 * 512];              // 32 KB
    __shared__ float2 tw[512];
    const int t = threadIdx.x;
    const int u = t >> 5;                       // FFT unit 0..7
    const int j = t & 31;
    const long long pair = (long long)blockIdx.x * 8 + u;   // 0..4095
    const float* x0 = img + pair * 1024;
    const float* x1 = x0 + 512;

    for (int i = t; i < 512; i += 256) tw[i] = twg[i];

    float2 v[16];
#pragma unroll
    for (int r = 0; r < 16; ++r)
        v[r] = make_float2(x0[j + 32 * r], x1[j + 32 * r]);
    __syncthreads();                            // tw ready

    // ---- stage h=256: pairs (r, r+8), pos = j+32r ----
#pragma unroll
    for (int r = 0; r < 8; ++r) {
        float2 w = tw[256 + j + 32 * r];
        float2 a = v[r], bb = v[r + 8];
        float dx = a.x - bb.x, dy = a.y - bb.y;
        v[r]     = make_float2(a.x + bb.x, a.y + bb.y);
        v[r + 8] = make_float2(dx * w.x - dy * w.y, dx * w.y + dy * w.x);
    }
    // ---- stage h=128 ----
#pragma unroll
    for (int g = 0; g < 2; ++g)
#pragma unroll
        for (int rr = 0; rr < 4; ++rr) {
            int r = g * 8 + rr;
            float2 w = tw[128 + j + 32 * rr];
            float2 a = v[r], bb = v[r + 4];
            float dx = a.x - bb.x, dy = a.y - bb.y;
            v[r]     = make_float2(a.x + bb.x, a.y + bb.y);
            v[r + 4] = make_float2(dx * w.x - dy * w.y, dx * w.y + dy * w.x);
        }
    // ---- stage h=64 ----
#pragma unroll
    for (int g = 0; g < 4; ++g)
#pragma unroll
        for (int rr = 0; rr < 2; ++rr) {
            int r = g * 4 + rr;
            float2 w = tw[64 + j + 32 * rr];
            float2 a = v[r], bb = v[r + 2];
            float dx = a.x - bb.x, dy = a.y - bb.y;
            v[r]     = make_float2(a.x + bb.x, a.y + bb.y);
            v[r + 2] = make_float2(dx * w.x - dy * w.y, dx * w.y + dy * w.x);
        }
    // ---- stage h=32 ----
    {
        float2 w = tw[32 + j];
#pragma unroll
        for (int g = 0; g < 8; ++g) {
            int r = g * 2;
            float2 a = v[r], bb = v[r + 1];
            float dx = a.x - bb.x, dy = a.y - bb.y;
            v[r]     = make_float2(a.x + bb.x, a.y + bb.y);
            v[r + 1] = make_float2(dx * w.x - dy * w.y, dx * w.y + dy * w.x);
        }
    }
    // ---- stages h=16..1 via shfl_xor ----
#pragma unroll
    for (int hs = 4; hs >= 0; --hs) {
        const int h = 1 << hs;
        float2 w = tw[h + (j & (h - 1))];
        const bool upper = (j & h) != 0;
#pragma unroll
        for (int r = 0; r < 16; ++r) {
            float ox = __shfl_xor(v[r].x, h);
            float oy = __shfl_xor(v[r].y, h);
            float sx = v[r].x + ox, sy = v[r].y + oy;
            float dx = ox - v[r].x, dy = oy - v[r].y;
            float tx = dx * w.x - dy * w.y, ty = dx * w.y + dy * w.x;
            v[r].x = upper ? tx : sx;
            v[r].y = upper ? ty : sy;
        }
    }

    // ---- stage Z to LDS for bit-reversed partner access ----
    float2* Z = sz + u * 512;
#pragma unroll
    for (int r = 0; r < 16; ++r) Z[j + 32 * r] = v[r];
    __syncthreads();

    // untangle: X0(k)=(Z(k)+conj(Z(-k)))/2, X1(k)=-i(Z(k)-conj(Z(-k)))/2
    h2* out0 = rowhf + pair * 1024;
#pragma unroll
    for (int r = 0; r < 16; ++r) {
        int i = j + 32 * r;
        int k = __brev((unsigned)i) >> 23;
        int kp = (512 - k) & 511;
        int jp = __brev((unsigned)kp) >> 23;
        float2 Zi = v[r], Zp = Z[jp];
        out0[i]       = h2{(_Float16)(0.5f * (Zi.x + Zp.x)),
                           (_Float16)(0.5f * (Zi.y - Zp.y))};
        out0[512 + i] = h2{(_Float16)(0.5f * (Zi.y + Zp.y)),
                           (_Float16)(-0.5f * (Zi.x - Zp.x))};
    }
}

// ===========================================================================
// FFT column pass — REGISTER FFT (r13 form: 3 blocks/CU, NOT cooperative —
// the 1-block/CU cooperative fusion regressed 78 µs from occupancy loss).
// ===========================================================================
#define FCOLS 16
__global__ void __launch_bounds__(512) fft_cols(const h2* __restrict__ rowhf,
                                                const float2* __restrict__ twg,
                                                _Float16* __restrict__ magT,
                                                float* __restrict__ psum,
                                                float* __restrict__ psumsq,
                                                unsigned* __restrict__ phist,
                                                unsigned* __restrict__ mhist) {
    __shared__ h2 sh[FCOLS * 512];              // 32 KB  [c][y]
    __shared__ float2 tw[512];                  // 4 KB
    __shared__ unsigned ph[64];
    __shared__ unsigned mh[NBIN];               // 8 KB
    __shared__ float red[16];
    const int t = threadIdx.x;
    const int b = blockIdx.x >> 5;              // 32 blocks per batch
    const int x0 = (blockIdx.x & 31) * FCOLS;

    for (int i = t; i < 512; i += 512) tw[i] = twg[i];
    if (t < 64) ph[t] = 0u;
    for (int i = t; i < NBIN; i += 512) mh[i] = 0u;
    for (int idx = t; idx < FCOLS * 512; idx += 512) {
        int y = idx >> 4, c = idx & 15;
        sh[c * 512 + y] = rowhf[((size_t)(b * 512 + y)) * 512 + x0 + c];
    }
    __syncthreads();

    const int c = t >> 5;                       // 0..15
    const int j = t & 31;
    float2 v[16];
#pragma unroll
    for (int r = 0; r < 16; ++r) {
        h2 hv = sh[c * 512 + j + 32 * r];
        v[r] = make_float2((float)hv[0], (float)hv[1]);
    }
    // ---- stage h=256 ----
#pragma unroll
    for (int r = 0; r < 8; ++r) {
        float2 w = tw[256 + j + 32 * r];
        float2 a = v[r], bb = v[r + 8];
        float dx = a.x - bb.x, dy = a.y - bb.y;
        v[r]     = make_float2(a.x + bb.x, a.y + bb.y);
        v[r + 8] = make_float2(dx * w.x - dy * w.y, dx * w.y + dy * w.x);
    }
    // ---- stage h=128 ----
#pragma unroll
    for (int g = 0; g < 2; ++g)
#pragma unroll
        for (int rr = 0; rr < 4; ++rr) {
            int r = g * 8 + rr;
            float2 w = tw[128 + j + 32 * rr];
            float2 a = v[r], bb = v[r + 4];
            float dx = a.x - bb.x, dy = a.y - bb.y;
            v[r]     = make_float2(a.x + bb.x, a.y + bb.y);
            v[r + 4] = make_float2(dx * w.x - dy * w.y, dx * w.y + dy * w.x);
        }
    // ---- stage h=64 ----
#pragma unroll
    for (int g = 0; g < 4; ++g)
#pragma unroll
        for (int rr = 0; rr < 2; ++rr) {
            int r = g * 4 + rr;
            float2 w = tw[64 + j + 32 * rr];
            float2 a = v[r], bb = v[r + 2];
            float dx = a.x - bb.x, dy = a.y - bb.y;
            v[r]     = make_float2(a.x + bb.x, a.y + bb.y);
            v[r + 2] = make_float2(dx * w.x - dy * w.y, dx * w.y + dy * w.x);
        }
    // ---- stage h=32 ----
    {
        float2 w = tw[32 + j];
#pragma unroll
        for (int g = 0; g < 8; ++g) {
            int r = g * 2;
            float2 a = v[r], bb = v[r + 1];
            float dx = a.x - bb.x, dy = a.y - bb.y;
            v[r]     = make_float2(a.x + bb.x, a.y + bb.y);
            v[r + 1] = make_float2(dx * w.x - dy * w.y, dx * w.y + dy * w.x);
        }
    }
    // ---- stages h=16..1: shuffle across lanes ----
#pragma unroll
    for (int hs = 4; hs >= 0; --hs) {
        const int h = 1 << hs;
        float2 w = tw[h + (j & (h - 1))];
        const bool upper = (j & h) != 0;
#pragma unroll
        for (int r = 0; r < 16; ++r) {
            float ox = __shfl_xor(v[r].x, h);
            float oy = __shfl_xor(v[r].y, h);
            float sx = v[r].x + ox, sy = v[r].y + oy;
            float dx = ox - v[r].x, dy = oy - v[r].y;
            float tx = dx * w.x - dy * w.y, ty = dx * w.y + dy * w.x;
            v[r].x = upper ? tx : sx;
            v[r].y = upper ? ty : sy;
        }
    }

    // ---- epilogue ----
    float lsum = 0.f, lsq = 0.f;
    _Float16* mcol = magT + ((size_t)(b * 512 + x0 + c)) * 512;
#pragma unroll
    for (int r = 0; r < 16; ++r) {
        float mag = sqrtf(v[r].x * v[r].x + v[r].y * v[r].y);
        union { _Float16 h; unsigned short u; } cvt;
        cvt.h = (_Float16)mag;
        mcol[j + 32 * r] = cvt.h;
        atomicAdd(&mh[min((unsigned)(cvt.u >> 4), (unsigned)(NBIN - 1))], 1u);
        float phv = atan2f(v[r].y, v[r].x);
        lsum += phv;
        lsq += phv * phv;
        int bin = min(max((int)floorf((phv + PI_F) / TWO_PI_F * 64.0f), 0), 63);
        atomicAdd(&ph[bin], 1u);
    }
    for (int off = 32; off > 0; off >>= 1) {
        lsum += __shfl_down(lsum, off);
        lsq  += __shfl_down(lsq, off);
    }
    if ((t & 63) == 0) { red[t >> 6] = lsum; red[8 + (t >> 6)] = lsq; }
    __syncthreads();
    if (t == 0) {
        float s = 0.f, q = 0.f;
        for (int i = 0; i < 8; ++i) { s += red[i]; q += red[8 + i]; }
        atomicAdd(psum + b, s);
        atomicAdd(psumsq + b, q);
    }
    if (t < 64 && ph[t]) atomicAdd(&phist[b * 64 + t], ph[t]);
    for (int i = t; i < NBIN; i += 512)
        if (mh[i]) atomicAdd(&mhist[b * NBIN + i], mh[i]);
}

// ===========================================================================
// top-k: threshold bin from histogram suffix-count
// ===========================================================================
__global__ void __launch_bounds__(256) thresh_kernel(const unsigned* __restrict__ mhist,
                                                     int* __restrict__ selbin) {
    __shared__ unsigned csum[256];
    const int b = blockIdx.x, t = threadIdx.x;
    unsigned s = 0;
    for (int i = 0; i < NBIN / 256; ++i) s += mhist[b * NBIN + t * (NBIN / 256) + i];
    csum[t] = s;
    __syncthreads();
    if (t == 0) {
        unsigned acc = 0; int chunk = 0;
        for (int i = 255; i >= 0; --i) {
            acc += csum[i];
            if (acc >= 128u) { chunk = i; break; }
        }
        unsigned acc2 = acc - csum[chunk];      // count strictly above chunk
        int tb = chunk * (NBIN / 256);
        for (int i = chunk * (NBIN / 256) + (NBIN / 256) - 1; i >= chunk * (NBIN / 256); --i) {
            acc2 += mhist[b * NBIN + i];
            if (acc2 >= 128u) { tb = i; break; }
        }
        selbin[b] = tb;
    }
}

// ===========================================================================
// top-k: parallel candidate collection (256 blocks, fp16 magT, uint4 loads)
// ===========================================================================
#define TK_CAP 4096
__global__ void __launch_bounds__(256) collect_kernel(const _Float16* __restrict__ magT,
                                                      const int* __restrict__ selbin,
                                                      float* __restrict__ cand,
                                                      unsigned* __restrict__ ccnt) {
    const int blk = blockIdx.x;
    const int b = blk >> 4, chunk = blk & 15;
    const unsigned tb = (unsigned)selbin[b];
    const uint4* m = (const uint4*)(magT + (size_t)b * 262144 + chunk * 16384);
    float* cb = cand + b * TK_CAP;
    for (int i = threadIdx.x; i < 2048; i += 256) {
        uint4 v4 = m[i];
        unsigned vv[4] = {v4.x, v4.y, v4.z, v4.w};
#pragma unroll
        for (int j = 0; j < 4; ++j) {
#pragma unroll
            for (int k = 0; k < 2; ++k) {
                unsigned short ub = (k == 0) ? (unsigned short)(vv[j] & 0xFFFFu)
                                             : (unsigned short)(vv[j] >> 16);
                if ((unsigned)(ub >> 4) >= tb) {
                    unsigned p = atomicAdd(&ccnt[b], 1u);
                    if (p < TK_CAP) {
                        union { unsigned short u; _Float16 h; } c2;
                        c2.u = ub;
                        cb[p] = (float)c2.h;
                    }
                }
            }
        }
    }
}

// ===========================================================================
// top-k: bitonic sort descending -> top-128 ; FUSED sims epilogue
// ===========================================================================
__global__ void __launch_bounds__(1024) sort_kernel(const float* __restrict__ cand,
                                                    const unsigned* __restrict__ ccnt,
                                                    const float* __restrict__ rec,
                                                    float* __restrict__ comb,
                                                    float* __restrict__ dout) {
    __shared__ float c[TK_CAP];
    const int b = blockIdx.x, t = threadIdx.x;
    const unsigned n = min(ccnt[b], (unsigned)TK_CAP);
    int P = 256;
    while (P < (int)n) P <<= 1;                 // 256..4096
    for (int i = t; i < P; i += 1024) c[i] = (i < (int)n) ? cand[b * TK_CAP + i] : -1.0f;
    __syncthreads();
    for (int k = 2; k <= P; k <<= 1) {
        for (int j = k >> 1; j > 0; j >>= 1) {
            for (int i = t; i < P; i += 1024) {
                int ixj = i ^ j;
                if (ixj > i) {
                    float a = c[i], d = c[ixj];
                    bool up = ((i & k) == 0);
                    if (up ? (a < d) : (a > d)) { c[i] = d; c[ixj] = a; }
                }
            }
            __syncthreads();
        }
    }
    // ---- sims epilogue: top-128 are c[0..127] ----
    if (t < 64) {
        float dn = 0.f;
        for (int k = 0; k < 128; ++k) dn += c[k] * c[k];
        const float* rv = rec + t * 128;
        float rn = 0.f, dot = 0.f;
        for (int k = 0; k < 128; ++k) {
            float r = rv[k];
            rn += r * r;
            dot += c[k] * r;
        }
        float val = dot / (fmaxf(sqrtf(dn), 1e-12f) * fmaxf(sqrtf(rn), 1e-12f));
        dout[b * 64 + t] = val;
        comb[b * 1091 + t] = val;
    }
}

// ===========================================================================
// FUSED gradient + conv1 + ReLU + maxpool2 -> h1 NHWC fp16, via MFMA
// implicit GEMM. Lane owns adjacent oc pair (2m, 2m+1) -> single h2 store.
// ===========================================================================
__global__ void __launch_bounds__(256) grad_conv1_mfma(const float* __restrict__ img,
                                                       const half8* __restrict__ w1r,
                                                       const float* __restrict__ c1b,
                                                       _Float16* __restrict__ h1) {
    __shared__ float simg[36 * 37];
    __shared__ _Float16 sgrad[(34 * 36 + 1) * 2];   // [(y+1)*36+(x+1)] -> (mag,ori); +1 zero pair
    const int blk = blockIdx.x;               // b*256 + tile
    const int b = blk >> 8;
    const int tr = blk & 255;                 // 16x16 tiles of 32 pre-pool px
    const int TY = (tr >> 4) * 32, TX = (tr & 15) * 32;
    const int t = threadIdx.x;
    const float* im = img + (long long)b * 262144;

    for (int idx = t; idx < 1296; idx += 256) {
        int iy = idx / 36, ix = idx - iy * 36;
        int gy = min(max(TY - 2 + iy, 0), 511);
        int gx = min(max(TX - 2 + ix, 0), 511);
        simg[iy * 37 + ix] = im[gy * 512 + gx];
    }
    if (t == 0) { sgrad[2448] = (_Float16)0.f; sgrad[2449] = (_Float16)0.f; }
    __syncthreads();

    for (int idx = t; idx < 1156; idx += 256) {
        int ly = idx / 34, lx = idx - ly * 34;       // 0..33
        int gy = TY - 1 + ly, gx = TX - 1 + lx;
        float up = simg[ly * 37 + lx + 1];
        float dn = simg[(ly + 2) * 37 + lx + 1];
        float lf = simg[(ly + 1) * 37 + lx];
        float rt = simg[(ly + 1) * 37 + lx + 2];
        float fy = (gy <= 0 || gy >= 511) ? 1.f : 0.5f;
        float fx = (gx <= 0 || gx >= 511) ? 1.f : 0.5f;
        float gyv = (dn - up) * fy, gxv = (rt - lf) * fx;
        bool inside = ((unsigned)gy < 512u) && ((unsigned)gx < 512u);
        float mag = inside ? sqrtf(gxv * gxv + gyv * gyv) : 0.f;
        float ori = inside ? atan2f(gyv, gxv) : 0.f;
        int p = (ly * 36 + lx) * 2;
        sgrad[p] = (_Float16)mag;
        sgrad[p + 1] = (_Float16)ori;
    }
    __syncthreads();

    const int w = t >> 6, lane = t & 63;
    const int q = lane >> 4, m = lane & 15;
    const int oc0 = 2 * m;                    // adjacent pair (paired repack)
    const float bias0 = c1b[oc0], bias1 = c1b[oc0 + 1];
    half8 Bf0 = w1r[lane], Bf1 = w1r[64 + lane];
    const unsigned* gp = (const unsigned*)sgrad;
    const int ZP = 1224;                      // zero pair index

    const int sy = (m >> 1) & 1, sx = m & 1, dqx = m >> 2;

#pragma unroll 4
    for (int i = 0; i < 16; ++i) {
        const int mt = w * 16 + i;            // 0..63
        const int qy = mt >> 2, qxg = mt & 3;
        const int py = 2 * qy + sy;
        const int px = 2 * (qxg * 4 + dqx) + sx;
        const int base = py * 36 + px;

        int o0 = (q == 0) ? base      : (q == 1) ? base + 37 : (q == 2) ? base + 74 : ZP;
        int o1 = (q == 0) ? base + 1  : (q == 1) ? base + 38 : ZP;
        int o2 = (q == 0) ? base + 2  : (q == 1) ? base + 72 : ZP;
        int o3 = (q == 0) ? base + 36 : (q == 1) ? base + 73 : ZP;

        union { unsigned u[4]; half8 h; } Af;
        Af.u[0] = gp[o0]; Af.u[1] = gp[o1]; Af.u[2] = gp[o2]; Af.u[3] = gp[o3];

        floatx4 acc0 = {bias0, bias0, bias0, bias0};
        floatx4 acc1 = {bias1, bias1, bias1, bias1};
        acc0 = __builtin_amdgcn_mfma_f32_16x16x32_f16(Af.h, Bf0, acc0, 0, 0, 0);
        acc1 = __builtin_amdgcn_mfma_f32_16x16x32_f16(Af.h, Bf1, acc1, 0, 0, 0);

        float v0 = fmaxf(fmaxf(acc0[0], acc0[1]), fmaxf(acc0[2], acc0[3]));
        float v1 = fmaxf(fmaxf(acc1[0], acc1[1]), fmaxf(acc1[2], acc1[3]));
        v0 = fmaxf(v0, 0.f);
        v1 = fmaxf(v1, 0.f);

        const int PY = (TY >> 1) + qy;
        const int PX = (TX >> 1) + qxg * 4 + q;
        _Float16* dst = h1 + (((size_t)(b * 256 + PY)) * 256 + PX) * 32;
        *(h2*)(dst + oc0) = h2{(_Float16)v0, (_Float16)v1};
    }
}

// ===========================================================================
// conv2 (32->64, 3x3 SAME) + ReLU + 64x64 avg-pool partials — implicit GEMM.
// FROZEN at r11 form (60 µs).
// ===========================================================================
__global__ void __launch_bounds__(256) conv2_mfma(const _Float16* __restrict__ h1,
                                                  const _Float16* __restrict__ wrep,
                                                  const float* __restrict__ c2b,
                                                  float* __restrict__ sacc) {
    __shared__ _Float16 tile[18 * 34 * 32];     // [row][px][ic] 39,168 B
    __shared__ float lsum[64];
    const int blk = blockIdx.x;                 // b*128 + yt*8 + xt
    const int b  = blk >> 7;
    const int yt = (blk >> 3) & 15;
    const int xt = blk & 7;
    const int y0 = yt * 16, x0 = xt * 32;
    const int t = threadIdx.x;
    if (t < 64) lsum[t] = 0.f;

    for (int c = t; c < 18 * 136; c += 256) {
        int row = c / 136;
        int chunk = c - row * 136;
        int gy = y0 - 1 + row;
        int px = chunk >> 2;
        int gx = x0 - 1 + px;
        floatx4 v = {0.f, 0.f, 0.f, 0.f};
        if ((unsigned)gy < 256u && (unsigned)gx < 256u)
            v = *(const floatx4*)(h1 + (((size_t)(b * 256 + gy)) * 256 + gx) * 32 + (chunk & 3) * 8);
        *(floatx4*)(tile + (row * 34 + px) * 32 + (chunk & 3) * 8) = v;
    }
    __syncthreads();

    const int w = t >> 6, lane = t & 63;
    const int q = lane >> 4, ln15 = lane & 15;
    float bias[4];
#pragma unroll
    for (int nt = 0; nt < 4; ++nt) bias[nt] = c2b[nt * 16 + ln15];
    float partial[4] = {0.f, 0.f, 0.f, 0.f};

#pragma unroll 1
    for (int gr = 0; gr < 2; ++gr) {
        floatx4 acc[4][4];
#pragma unroll
        for (int mt = 0; mt < 4; ++mt)
#pragma unroll
            for (int nt = 0; nt < 4; ++nt)
                acc[mt][nt] = floatx4{bias[nt], bias[nt], bias[nt], bias[nt]};

        const _Float16* ab = tile + (((w * 4 + gr * 2) * 34) + ln15) * 32 + q * 8;
        const _Float16* wk = wrep + lane * 8;   // advances 2048 halfs per tap

#pragma unroll 1
        for (int ky = 0; ky < 3; ++ky) {
#pragma unroll
            for (int kx = 0; kx < 3; ++kx) {
                half8 Bf[4];
#pragma unroll
                for (int nt = 0; nt < 4; ++nt)
                    Bf[nt] = *(const half8*)(wk + (kx * 4 + nt) * 512);
#pragma unroll
                for (int mt = 0; mt < 4; ++mt) {
                    half8 Af = *(const half8*)(ab + (mt >> 1) * 1088 + (mt & 1) * 512 + kx * 32);
#pragma unroll
                    for (int nt = 0; nt < 4; ++nt)
                        acc[mt][nt] = __builtin_amdgcn_mfma_f32_16x16x32_f16(Af, Bf[nt], acc[mt][nt], 0, 0, 0);
                }
            }
            ab += 34 * 32;                      // next ky row
            wk += 3 * 2048;                     // next tap row (3 taps)
        }

#pragma unroll
        for (int mt = 0; mt < 4; ++mt)
#pragma unroll
            for (int nt = 0; nt < 4; ++nt)
#pragma unroll
                for (int rg = 0; rg < 4; ++rg)
                    partial[nt] += fmaxf(acc[mt][nt][rg], 0.f);
    }

#pragma unroll
    for (int nt = 0; nt < 4; ++nt) {
        float v = partial[nt];
        v += __shfl_xor(v, 16);
        v += __shfl_xor(v, 32);
        if (lane < 16) atomicAdd(&lsum[nt * 16 + ln15], v);
    }
    __syncthreads();
    const int cell = (yt >> 2) * 4 + (xt >> 1);
    if (t < 64) atomicAdd(&sacc[(((b << 6) + t) << 4) + cell], lsum[t]);
}

// ===========================================================================
// combined finalize: blocks 0..63 spatial, block 64 phase
// ===========================================================================
__global__ void __launch_bounds__(256) finalize_kernel(const float* __restrict__ sacc,
                                                       const float* __restrict__ psum,
                                                       const float* __restrict__ psumsq,
                                                       const unsigned* __restrict__ phist,
                                                       float* __restrict__ comb,
                                                       float* __restrict__ dout) {
    if (blockIdx.x < 64) {
        int idx = blockIdx.x * 256 + threadIdx.x;     // 16384
        int b = idx >> 10, j = idx & 1023;
        float v = sacc[idx] * (1.0f / 4096.0f);
        dout[1024 + idx] = v;
        comb[b * 1091 + 64 + j] = v;
    } else {
        int t = threadIdx.x;
        if (t < 16) {
            const float N = 262144.f;
            float s = psum[t];
            float mean = s / N;
            float var = (psumsq[t] - s * s / N) / (N - 1.f);
            float sd = sqrtf(fmaxf(var, 0.f));
            float ent = 0.f;
            for (int i = 0; i < 64; ++i) {
                float p = (float)phist[t * 64 + i] / N;
                ent -= p * logf(p + 1e-10f);
            }
            dout[17408 + t * 3 + 0] = mean;
            dout[17408 + t * 3 + 1] = sd;
            dout[17408 + t * 3 + 2] = ent;
            float* cb = comb + t * 1091 + 1088;
            cb[0] = mean; cb[1] = sd; cb[2] = ent;
        }
    }
}

// ===========================================================================
// fc1: wave per (b,o), coalesced weight-row sweep + shuffle reduce
// ===========================================================================
__global__ void __launch_bounds__(256) fc1_kernel(const float* __restrict__ comb,
                                                  const float* __restrict__ W1,
                                                  const float* __restrict__ B1,
                                                  float* __restrict__ out1) {
    const int wid = blockIdx.x * 4 + (threadIdx.x >> 6);  // 0..8191
    const int lane = threadIdx.x & 63;
    const int b = wid >> 9, o = wid & 511;
    const float* w = W1 + (size_t)o * 1091;
    const float* c = comb + b * 1091;
    float acc = 0.f;
#pragma unroll 4
    for (int i = 0; i < 17; ++i) {
        int k = i * 64 + lane;
        acc += w[k] * c[k];                     // 17*64 = 1088
    }
    if (lane < 3) acc += w[1088 + lane] * c[1088 + lane];
#pragma unroll
    for (int off = 32; off > 0; off >>= 1) acc += __shfl_down(acc, off);
    if (lane == 0) out1[b * 512 + o] = fmaxf(acc + B1[o], 0.f);
}

// ===========================================================================
// fc2: wave per (b,o)
// ===========================================================================
__global__ void __launch_bounds__(256) fc2_kernel(const float* __restrict__ out1,
                                                  const float* __restrict__ W2,
                                                  const float* __restrict__ B2,
                                                  float* __restrict__ z) {
    const int wid = blockIdx.x * 4 + (threadIdx.x >> 6);  // 0..2047
    const int lane = threadIdx.x & 63;
    const int b = wid >> 7, o = wid & 127;
    const float* w = W2 + (size_t)o * 512;
    const float* c = out1 + b * 512;
    float acc = 0.f;
#pragma unroll
    for (int i = 0; i < 8; ++i) {
        int k = i * 64 + lane;
        acc += w[k] * c[k];
    }
#pragma unroll
    for (int off = 32; off > 0; off >>= 1) acc += __shfl_down(acc, off);
    if (lane == 0) z[b * 128 + o] = acc + B2[o];
}

// ===========================================================================
// layernorm over z[16,128] -> holo
// ===========================================================================
__global__ void __launch_bounds__(128) ln_kernel(const float* __restrict__ z,
                                                 const float* __restrict__ g,
                                                 const float* __restrict__ beta,
                                                 float* __restrict__ dout) {
    __shared__ float red[4];
    const int b = blockIdx.x, t = threadIdx.x;
    float acc = z[b * 128 + t];
    float s = acc;
    for (int off = 32; off > 0; off >>= 1) s += __shfl_down(s, off);
    if ((t & 63) == 0) red[t >> 6] = s;
    __syncthreads();
    float mu = (red[0] + red[1]) * (1.0f / 128.0f);
    float d = acc - mu;
    float q = d * d;
    for (int off = 32; off > 0; off >>= 1) q += __shfl_down(q, off);
    if ((t & 63) == 0) red[2 + (t >> 6)] = q;
    __syncthreads();
    float var = (red[2] + red[3]) * (1.0f / 128.0f);
    dout[17456 + b * 128 + t] = d / sqrtf(var + 1e-5f) * g[t] + beta[t];
}

// ===========================================================================
// launcher
// ===========================================================================
extern "C" void kernel_launch(void* const* d_in, const int* in_sizes, int n_in,
                              void* d_out, int out_size, void* d_ws, size_t ws_size,
                              hipStream_t stream) {
    const float* img = (const float*)d_in[0];
    const float* rec = (const float*)d_in[1];
    const float* w1  = (const float*)d_in[2];
    const float* c1b = (const float*)d_in[3];
    const float* w2  = (const float*)d_in[4];
    const float* c2b = (const float*)d_in[5];
    const float* fw1 = (const float*)d_in[6];
    const float* fb1 = (const float*)d_in[7];
    const float* fw2 = (const float*)d_in[8];
    const float* fb2 = (const float*)d_in[9];
    const float* lng = (const float*)d_in[10];
    const float* lnb = (const float*)d_in[11];
    float* out = (float*)d_out;

    float* ws = (float*)d_ws;
    h2* rowhf       = (h2*)ws;                    // region0: 16*512*512 half2 = 16.8 MB
    _Float16* magT  = (_Float16*)(ws + OFF_BIG);  // region1: fp16 mags 33.5 MB
    _Float16* h1    = (_Float16*)(ws + OFF_BIG);  // alias (magT dead after collect) NHWC
    float* small_  = ws + OFF_SMALL;
    float* sacc    = small_;                      // 16384
    float* psum    = small_ + 16384;              // 16
    float* psumsq  = small_ + 16400;              // 16
    unsigned* phist = (unsigned*)(small_ + 16416);// 1024
    unsigned* mhist = (unsigned*)(small_ + 17440);// NBIN*16 = 32768 (region sized 65536)
    unsigned* ccnt  = (unsigned*)(small_ + 82976);// 16    (zeroed range ends at 82992)
    int* selbin    = (int*)(small_ + 82992);      // 16
    float* comb    = small_ + 85056;              // 17456
    float* out1    = small_ + 102512;             // 8192
    _Float16* wrep = (_Float16*)(small_ + 110704);// 18432 f16 = 9216 dwords
    float2* twg    = (float2*)(small_ + 119920);  // 512 float2 = 1024 dwords
    float* cand    = small_ + 120944;             // 16*4096 = 65536 dwords
    float* zbuf    = cand;                        // alias (cand dead after sort)
    _Float16* w1r  = (_Float16*)(small_ + 186480);// 1024 f16 = 512 dwords

    init_kernel<<<325, 256, 0, stream>>>(sacc, twg, w2, w1, wrep, w1r);
    fft_rows2<<<512, 256, 0, stream>>>(img, twg, rowhf);
    fft_cols<<<512, 512, 0, stream>>>(rowhf, twg, magT, psum, psumsq, phist, mhist);
    thresh_kernel<<<16, 256, 0, stream>>>(mhist, selbin);
    collect_kernel<<<256, 256, 0, stream>>>(magT, selbin, cand, ccnt);
    sort_kernel<<<16, 1024, 0, stream>>>(cand, ccnt, rec, comb, out);
    grad_conv1_mfma<<<4096, 256, 0, stream>>>(img, (const half8*)w1r, c1b, h1);
    conv2_mfma<<<2048, 256, 0, stream>>>(h1, wrep, c2b, sacc);
    finalize_kernel<<<65, 256, 0, stream>>>(sacc, psum, psumsq, phist, comb, out);
    fc1_kernel<<<2048, 256, 0, stream>>>(comb, fw1, fb1, out1);
    fc2_kernel<<<512, 256, 0, stream>>>(out1, fw2, fb2, zbuf);
    ln_kernel<<<16, 128, 0, stream>>>(zbuf, lng, lnb, out);
}